// Round 10
// baseline (1079.247 us; speedup 1.0000x reference)
//
#include <hip/hip_runtime.h>
#include <hip/hip_bf16.h>

typedef __hip_bfloat16 bf16;
typedef __attribute__((ext_vector_type(8))) short short8;
typedef __attribute__((ext_vector_type(4))) short s16x4;
typedef __attribute__((ext_vector_type(4))) float f32x4;
typedef __attribute__((ext_vector_type(2))) float f32x2;

#define TB 128      // batch
#define TT 128      // time
#define EMB 512     // embed dim
#define HH 512      // per-direction hidden
#define G4 2048     // 4*HH gate dim
#define NROWS 512   // 4 runs * 128 batch
#define F4 4096     // feature dim
#define HD 1024     // mlp hidden

__device__ __forceinline__ bf16 f2bf(float x){ return __float2bfloat16(x); }
__device__ __forceinline__ float bf2f(bf16 x){ return __bfloat162float(x); }

// fast gates: v_exp_f32 + v_rcp_f32; saturate cleanly (rcp(inf)=0), no NaN
__device__ __forceinline__ float fsigm(float x){
    return __builtin_amdgcn_rcpf(1.f + __builtin_amdgcn_exp2f(-1.44269504089f * x));
}
__device__ __forceinline__ float ftanh(float x){
    float t = __builtin_amdgcn_exp2f(2.88539008178f * x);
    return 1.f - 2.f * __builtin_amdgcn_rcpf(t + 1.f);
}

__device__ __forceinline__ short8 pack8(float4 a, float4 b){
    short8 r;
    r[0] = (short)__bfloat16_as_ushort(f2bf(a.x));
    r[1] = (short)__bfloat16_as_ushort(f2bf(a.y));
    r[2] = (short)__bfloat16_as_ushort(f2bf(a.z));
    r[3] = (short)__bfloat16_as_ushort(f2bf(a.w));
    r[4] = (short)__bfloat16_as_ushort(f2bf(b.x));
    r[5] = (short)__bfloat16_as_ushort(f2bf(b.y));
    r[6] = (short)__bfloat16_as_ushort(f2bf(b.z));
    r[7] = (short)__bfloat16_as_ushort(f2bf(b.w));
    return r;
}

// ---------------------------------------------------------------------------
// f32 -> bf16 conversion
// ---------------------------------------------------------------------------
__global__ __launch_bounds__(256) void k_cvt(const float* __restrict__ src,
                                             bf16* __restrict__ dst, int n4)
{
    for (int i = blockIdx.x * 256 + threadIdx.x; i < n4; i += gridDim.x * 256) {
        float4 v = reinterpret_cast<const float4*>(src)[i];
        s16x4 o;
        o[0] = (short)__bfloat16_as_ushort(f2bf(v.x));
        o[1] = (short)__bfloat16_as_ushort(f2bf(v.y));
        o[2] = (short)__bfloat16_as_ushort(f2bf(v.z));
        o[3] = (short)__bfloat16_as_ushort(f2bf(v.w));
        reinterpret_cast<s16x4*>(dst)[i] = o;
    }
}

// ---------------------------------------------------------------------------
// Gather embed rows to bf16 x_bf[s][t][b][e]  (fallback-1 path only)
// ---------------------------------------------------------------------------
__global__ __launch_bounds__(256) void k_gather(
    const int* __restrict__ tok_h, const int* __restrict__ tok_p,
    const float* __restrict__ embed, bf16* __restrict__ x_bf)
{
    const int total4 = 2 * TT * TB * (EMB / 4);
    for (int g = blockIdx.x * 256 + threadIdx.x; g < total4; g += gridDim.x * 256) {
        int e4 = g & (EMB / 4 - 1);
        int b  = (g >> 7) & 127;
        int t  = (g >> 14) & 127;
        int s  = g >> 21;
        int tok = (s ? tok_p : tok_h)[b * TT + t];
        float4 v = reinterpret_cast<const float4*>(embed + (size_t)tok * EMB)[e4];
        s16x4 o;
        o[0] = (short)__bfloat16_as_ushort(f2bf(v.x));
        o[1] = (short)__bfloat16_as_ushort(f2bf(v.y));
        o[2] = (short)__bfloat16_as_ushort(f2bf(v.z));
        o[3] = (short)__bfloat16_as_ushort(f2bf(v.w));
        reinterpret_cast<s16x4*>(x_bf + (((size_t)s * TT + t) * TB + b) * EMB)[e4] = o;
    }
}

// ---------------------------------------------------------------------------
// xg[m][g] = embed[tok(m)] . W_ih[g] + b_ih[g] + b_hh[g]   (bf16 out)
// grid (512, 8): mb fastest (same-A blocks co-XCD). B = pre-cvt bf16 W_ihb.
// ---------------------------------------------------------------------------
__global__ __launch_bounds__(256) void k_xproj2(
    const int* __restrict__ tok_h, const int* __restrict__ tok_p,
    const float* __restrict__ embed, const bf16* __restrict__ W_ihb,
    const float* __restrict__ b_ih, const float* __restrict__ b_hh,
    bf16* __restrict__ xg)
{
    __shared__ __align__(16) short As[64][512];
    const int mb = blockIdx.x;      // 0..511 (64-row slabs)  [fastest dim]
    const int nb = blockIdx.y;      // 0..7 (256-col slabs)
    const int tid = threadIdx.x;
    const int w = tid >> 6, lane = tid & 63, l16 = lane & 15, kq = lane >> 4;
    const int m0 = mb * 64;
    const int s  = m0 >> 14;
    const int tt = (m0 >> 7) & 127;
    const int bbase = m0 & 127;     // 0 or 64
    const int* tp = s ? tok_p : tok_h;

#pragma unroll
    for (int it = 0; it < 16; ++it) {
        int idx = it * 256 + tid;
        int row = idx >> 6;
        int ch  = idx & 63;
        int tok = tp[(bbase + row) * TT + tt];
        const float* er = embed + (size_t)tok * EMB + ch * 8;
        float4 v0 = *(const float4*)er;
        float4 v1 = *(const float4*)(er + 4);
        *(short8*)&As[row][(ch ^ (row & 7)) * 8] = pack8(v0, v1);
    }
    __syncthreads();

    const int c0 = nb * 256 + w * 64;
    f32x4 acc[4][4];
#pragma unroll
    for (int mt = 0; mt < 4; ++mt)
#pragma unroll
        for (int nt = 0; nt < 4; ++nt) acc[mt][nt] = (f32x4)0.f;

    for (int kk = 0; kk < 16; ++kk) {
        short8 bfr[4];
#pragma unroll
        for (int nt = 0; nt < 4; ++nt)
            bfr[nt] = *(const short8*)(W_ihb + (size_t)(c0 + nt * 16 + l16) * EMB + kk * 32 + kq * 8);
#pragma unroll
        for (int mt = 0; mt < 4; ++mt) {
            int row = mt * 16 + l16;
            short8 a = *(const short8*)&As[row][(((kk * 4 + kq) ^ (row & 7)) * 8)];
#pragma unroll
            for (int nt = 0; nt < 4; ++nt)
                acc[mt][nt] = __builtin_amdgcn_mfma_f32_16x16x32_bf16(a, bfr[nt], acc[mt][nt], 0, 0, 0);
        }
    }
#pragma unroll
    for (int nt = 0; nt < 4; ++nt) {
        int col = c0 + nt * 16 + l16;
        float bias = b_ih[col] + b_hh[col];
#pragma unroll
        for (int mt = 0; mt < 4; ++mt)
#pragma unroll
            for (int q = 0; q < 4; ++q) {
                int m = m0 + mt * 16 + kq * 4 + q;
                xg[(size_t)m * G4 + col] = f2bf(acc[mt][nt][q] + bias);
            }
    }
}

// ---------------------------------------------------------------------------
// PERSISTENT LSTM v7 (cooperative). v6 + :
//  - flags ALSO via local-XCD L2 (sc0) when co-located; every 32nd poll
//    sweep uses the proven agent atomic (staleness bound -> no hang)
//  - fast sigmoid/tanh via v_exp_f32/v_rcp_f32
//  - ga pad 17 -> 18 (gate-exchange writes 4-way -> 2-way banks)
// ---------------------------------------------------------------------------
__global__ __launch_bounds__(512, 1) void k_persist7(
    const bf16* __restrict__ xg, const float* __restrict__ W_hh,
    const float* __restrict__ b_ih, const float* __restrict__ b_hh,
    float* __restrict__ h_f32, float* __restrict__ h_fin,
    int* __restrict__ slots, int* __restrict__ xinfo)
{
    __shared__ __align__(16) short hstage[2][16][512];   // 32 KB (hi,lo)
    __shared__ float ga[16][16][18];                     // 18 KB

    const int tid = threadIdx.x;
    const int bid = blockIdx.x;
    const int rg = bid & 31;          // rgroup (16 rows); bid%8 == rg%8
    const int cb = bid >> 5;          // 0..7 col-block (64 h-cols)
    const int w = tid >> 6, lane = tid & 63, l16 = lane & 15, kq = lane >> 4;
    const int j0 = cb * 64;
    const int r0 = rg * 16;
    const int run = rg >> 3;          // 0 hypF, 1 hypB, 2 premF, 3 premB
    const int s = run >> 1, dirb = run & 1;
    const int b0 = (rg & 7) * 16;

    // ---- co-location detection (safe under cooperative residency) ----
    bool mall = false;
    {
        int myx;
        asm volatile("s_getreg_b32 %0, hwreg(HW_REG_XCC_ID)" : "=s"(myx));
        if (tid == 0)
            __hip_atomic_store(&xinfo[bid], (myx & 15) + 1,
                               __ATOMIC_RELAXED, __HIP_MEMORY_SCOPE_AGENT);
        int v0 = 0;
        for (int c = 0; c < 8; ++c) {
            int v;
            do {
                v = __hip_atomic_load(&xinfo[c * 32 + rg],
                                      __ATOMIC_RELAXED, __HIP_MEMORY_SCOPE_AGENT);
                if (!v) __builtin_amdgcn_s_sleep(2);
            } while (!v);
            if (c == 0) v0 = v;
            else if (v != v0) mall = true;
        }
    }

    // ---- W_hh register frags: wave w owns ntiles 2w, 2w+1 ----
    short8 Bf[2][16];
#pragma unroll
    for (int nt = 0; nt < 2; ++nt) {
        int n = 2 * w + nt;
        int gcol = (n >> 2) * HH + j0 + (n & 3) * 16 + l16;
        const float* wr = W_hh + (size_t)gcol * HH;
#pragma unroll
        for (int kk = 0; kk < 16; ++kk) {
            float4 v0 = *(const float4*)(wr + kk * 32 + kq * 8);
            float4 v1 = *(const float4*)(wr + kk * 32 + kq * 8 + 4);
            Bf[nt][kk] = pack8(v0, v1);
        }
    }

    const int urow = tid >> 5;        // 0..15
    const int jseg = tid & 31;        // 16-f32 segment / 2-cell col pair
    float bsum[2][4];
#pragma unroll
    for (int e = 0; e < 2; ++e)
#pragma unroll
        for (int g = 0; g < 4; ++g) {
            int j = g * HH + j0 + jseg * 2 + e;
            bsum[e][g] = b_ih[j] + b_hh[j];
        }
    float creg[2] = {0.f, 0.f};
    const size_t HSF = (size_t)NROWS * HH;

    // xg element offsets for this thread's 8 acc-init values
    int rowoff[8];
#pragma unroll
    for (int nt = 0; nt < 2; ++nt) {
        int n = 2 * w + nt;
        int gcol = (n >> 2) * HH + j0 + (n & 3) * 16 + l16;
#pragma unroll
        for (int q = 0; q < 4; ++q)
            rowoff[nt * 4 + q] = (b0 + kq * 4 + q) * G4 + gcol;
    }

    // prologue: xg prefetch for t=0 (normal cached loads)
    unsigned xp[8];
    {
        int te0 = dirb ? (TT - 1) : 0;
        const bf16* xr = xg + ((size_t)(s * TT + te0) * TB) * G4;
#pragma unroll
        for (int i = 0; i < 8; ++i)
            xp[i] = (unsigned)__bfloat16_as_ushort(xr[rowoff[i]]);
    }

    for (int t = 0; t < TT; ++t) {
        const int p = t & 1;

        // ---- h loads: local-XCD L2 (sc0) if co-located, else MALL ----
        f32x4 hv[4];
        {
            unsigned long long a = (unsigned long long)(
                h_f32 + (size_t)p * HSF + (size_t)(r0 + urow) * HH + jseg * 16);
            if (mall) {
#pragma unroll
                for (int i = 0; i < 4; ++i)
                    asm volatile("global_load_dwordx4 %0, %1, off sc0 sc1"
                                 : "=v"(hv[i]) : "v"(a + i * 16));
            } else {
#pragma unroll
                for (int i = 0; i < 4; ++i)
                    asm volatile("global_load_dwordx4 %0, %1, off sc0"
                                 : "=v"(hv[i]) : "v"(a + i * 16));
            }
        }
        asm volatile("s_waitcnt vmcnt(0)" ::: "memory");
        __builtin_amdgcn_sched_barrier(0);

        // ---- stage hi/lo to LDS (XOR-swizzled) ----
#pragma unroll
        for (int half = 0; half < 2; ++half) {
            short8 hi, lo;
#pragma unroll
            for (int i2 = 0; i2 < 8; ++i2) {
                float v = hv[half * 2 + (i2 >> 2)][i2 & 3];
                bf16 hb = f2bf(v);
                hi[i2] = (short)__bfloat16_as_ushort(hb);
                lo[i2] = (short)__bfloat16_as_ushort(f2bf(v - bf2f(hb)));
            }
            int ch = (2 * jseg + half) ^ (urow & 7);
            *(short8*)&hstage[0][urow][ch * 8] = hi;
            *(short8*)&hstage[1][urow][ch * 8] = lo;
        }

        // acc init from prefetched xg bits (bf16 -> f32 is a shift)
        f32x4 acc[2];
#pragma unroll
        for (int nt = 0; nt < 2; ++nt)
#pragma unroll
            for (int q = 0; q < 4; ++q)
                acc[nt][q] = __uint_as_float(xp[nt * 4 + q] << 16);

        __syncthreads();   // sync #1: hstage ready

        // ---- MFMA: gates += (h_lo + h_hi) @ W_hh^T ----
#pragma unroll
        for (int kk = 0; kk < 16; ++kk) {
            int ch = ((kk * 4 + kq) ^ (l16 & 7)) * 8;
            short8 ahi = *(const short8*)&hstage[0][l16][ch];
            short8 alo = *(const short8*)&hstage[1][l16][ch];
#pragma unroll
            for (int nt = 0; nt < 2; ++nt) {
                acc[nt] = __builtin_amdgcn_mfma_f32_16x16x32_bf16(alo, Bf[nt][kk], acc[nt], 0, 0, 0);
                acc[nt] = __builtin_amdgcn_mfma_f32_16x16x32_bf16(ahi, Bf[nt][kk], acc[nt], 0, 0, 0);
            }
        }

        // ---- gate exchange ----
#pragma unroll
        for (int nt = 0; nt < 2; ++nt)
#pragma unroll
            for (int q = 0; q < 4; ++q)
                ga[2 * w + nt][kq * 4 + q][l16] = acc[nt][q];
        __syncthreads();   // sync #2: ga ready

        // ---- cell update (fast gates) ----
        float hn2[2];
#pragma unroll
        for (int e = 0; e < 2; ++e) {
            int jc = jseg * 2 + e;
            int sub = jc >> 4, c15 = jc & 15;
            float pi = ga[0 + sub][urow][c15]  + bsum[e][0];
            float pf = ga[4 + sub][urow][c15]  + bsum[e][1];
            float pg = ga[8 + sub][urow][c15]  + bsum[e][2];
            float po = ga[12 + sub][urow][c15] + bsum[e][3];
            float cn = fsigm(pf) * creg[e] + fsigm(pi) * ftanh(pg);
            float hn = fsigm(po) * ftanh(cn);
            creg[e] = cn;
            hn2[e] = hn;
        }
        // h store — first vmem op after full drain
        {
            unsigned long long a = (unsigned long long)(
                h_f32 + (size_t)(p ^ 1) * HSF + (size_t)(r0 + urow) * HH + j0 + jseg * 2);
            f32x2 val; val[0] = hn2[0]; val[1] = hn2[1];
            if (mall)
                asm volatile("global_store_dwordx2 %0, %1, off sc0 sc1"
                             :: "v"(a), "v"(val) : "memory");
            else
                asm volatile("global_store_dwordx2 %0, %1, off sc0"
                             :: "v"(a), "v"(val) : "memory");
        }
        if (t == TT - 1) {
            size_t fb = (size_t)(r0 + urow) * HH + j0 + jseg * 2;
            h_fin[fb] = hn2[0];
            h_fin[fb + 1] = hn2[1];
            break;
        }

        // ---- xg prefetch for t+1 (issued after store; vmcnt(8) => store done)
        {
            int ten = dirb ? (TT - 2 - t) : (t + 1);
            const bf16* xrn = xg + ((size_t)(s * TT + ten) * TB) * G4;
#pragma unroll
            for (int i = 0; i < 8; ++i)
                asm volatile("global_load_ushort %0, %1, off"
                             : "=v"(xp[i])
                             : "v"((unsigned long long)(xrn + rowoff[i])));
        }
        asm volatile("s_waitcnt vmcnt(8)" ::: "memory");  // h store drained
        __syncthreads();   // sync #3: all waves' stores drained
        if (tid == 0) {
            if (mall)
                __hip_atomic_store(&slots[rg * 8 + cb], t + 1,
                                   __ATOMIC_RELAXED, __HIP_MEMORY_SCOPE_AGENT);
            else
                asm volatile("global_store_dword %0, %1, off sc0"
                             :: "v"((unsigned long long)(slots + rg * 8 + cb)),
                                "v"(t + 1) : "memory");
        }
        // ---- all-wave poll: fast sc0 path, agent-atomic safety every 32 ----
        {
            int sidx = rg * 8 + (lane & 7);
            unsigned long long sa = (unsigned long long)(slots + sidx);
            int it = 0;
            while (true) {
                int v;
                if (mall || ((++it & 31) == 0)) {
                    v = __hip_atomic_load(&slots[sidx],
                                          __ATOMIC_RELAXED, __HIP_MEMORY_SCOPE_AGENT);
                } else {
                    asm volatile("global_load_dword %0, %1, off sc0\n\ts_waitcnt vmcnt(0)"
                                 : "=v"(v) : "v"(sa) : "memory");
                }
                v = (lane < 8) ? v : 0x7fffffff;
                if (__all(v >= t + 1)) break;
                __builtin_amdgcn_s_sleep(1);
            }
        }
    }
}

// ---------------------------------------------------------------------------
// FALLBACK-1: cooperative persistent kernel (round-4 proven)
// ---------------------------------------------------------------------------
__global__ __launch_bounds__(256) void k_persist(
    const bf16* __restrict__ x_bf,
    const float* __restrict__ W_ih, const float* __restrict__ W_hh,
    const float* __restrict__ b_ih, const float* __restrict__ b_hh,
    bf16* __restrict__ h_hi, bf16* __restrict__ h_lo,
    float* __restrict__ h_fin, int* slots)
{
    __shared__ short Wl[4 * 16 * 16 * 64];
    __shared__ float ga[4][64][17];

    const int tid = threadIdx.x;
    const int bx  = blockIdx.x;
    const int mi  = bx & 7;
    const int cj  = bx >> 3;
    const int w    = tid >> 6;
    const int lane = tid & 63;
    const int l16 = lane & 15;
    const int kq  = lane >> 4;
    const int j0  = cj * 16;
    const int r0  = mi * 64;
    const int run = mi >> 1;
    const int s   = run >> 1;
    const int dirb = run & 1;

    {
        int gc  = tid >> 2;
        int g   = gc >> 4, c = gc & 15;
        int kq4 = tid & 3;
        const float* wxr = W_ih + (size_t)(g * HH + j0 + c) * EMB;
        const float* whr = W_hh + (size_t)(g * HH + j0 + c) * HH;
        for (int kb = 0; kb < 16; ++kb) {
            int k  = kq4 * 128 + kb * 8;
            int kk = k >> 5;
            int eq = (k >> 3) & 3;
            float4 x0 = *(const float4*)(wxr + k);
            float4 x1 = *(const float4*)(wxr + k + 4);
            float4 h0 = *(const float4*)(whr + k);
            float4 h1 = *(const float4*)(whr + k + 4);
            int base = ((g * 16 + kk) * 16 + c) * 64;
            int sx = eq ^ (c & 7);
            int sh = (eq + 4) ^ (c & 7);
            *(short8*)&Wl[base + sx * 8] = pack8(x0, x1);
            *(short8*)&Wl[base + sh * 8] = pack8(h0, h1);
        }
    }

    float bsum[4];
    {
        int j = j0 + (tid & 15);
#pragma unroll
        for (int g = 0; g < 4; ++g) bsum[g] = b_ih[g * HH + j] + b_hh[g * HH + j];
    }
    float creg[4] = {0.f, 0.f, 0.f, 0.f};
    __syncthreads();

    const size_t HS = (size_t)NROWS * HH;
    for (int t = 0; t < TT; ++t) {
        const int p  = t & 1;
        const int te = dirb ? (TT - 1 - t) : t;
        const bf16* hb = h_hi + (size_t)p * HS;
        const bf16* lb = h_lo + (size_t)p * HS;
        const bf16* xr0 = x_bf + ((size_t)(s * TT + te) * TB) * EMB;

        f32x4 acc[4];
#pragma unroll
        for (int mt = 0; mt < 4; ++mt) acc[mt] = (f32x4)0.f;

        const bf16 *ph[4], *pl[4], *px[4];
#pragma unroll
        for (int mt = 0; mt < 4; ++mt) {
            int r = r0 + mt * 16 + l16;
            ph[mt] = hb + (size_t)r * HH;
            pl[mt] = lb + (size_t)r * HH;
            px[mt] = xr0 + (size_t)(r & 127) * EMB;
        }

        for (int kk = 0; kk < 16; ++kk) {
            int cbse = ((w * 16 + kk) * 16 + l16) * 64;
            short8 fx = *(const short8*)&Wl[cbse + ((kq ^ (lane & 7)) * 8)];
            short8 fh = *(const short8*)&Wl[cbse + (((kq + 4) ^ (lane & 7)) * 8)];
            int k0 = kk * 32 + kq * 8;
#pragma unroll
            for (int mt = 0; mt < 4; ++mt) {
                short8 ax  = *(const short8*)(px[mt] + k0);
                short8 ahi = *(const short8*)(ph[mt] + k0);
                short8 alo = *(const short8*)(pl[mt] + k0);
                acc[mt] = __builtin_amdgcn_mfma_f32_16x16x32_bf16(ax,  fx, acc[mt], 0, 0, 0);
                acc[mt] = __builtin_amdgcn_mfma_f32_16x16x32_bf16(alo, fh, acc[mt], 0, 0, 0);
                acc[mt] = __builtin_amdgcn_mfma_f32_16x16x32_bf16(ahi, fh, acc[mt], 0, 0, 0);
            }
        }
#pragma unroll
        for (int mt = 0; mt < 4; ++mt)
#pragma unroll
            for (int q = 0; q < 4; ++q)
                ga[w][mt * 16 + kq * 4 + q][l16] = acc[mt][q];
        __syncthreads();

        bf16* hob = h_hi + (size_t)(p ^ 1) * HS;
        bf16* lob = h_lo + (size_t)(p ^ 1) * HS;
        const int colc = tid & 15;
        const int j = j0 + colc;
#pragma unroll
        for (int q = 0; q < 4; ++q) {
            int rl = (tid >> 4) + q * 16;
            int r  = r0 + rl;
            float pi = ga[0][rl][colc] + bsum[0];
            float pf = ga[1][rl][colc] + bsum[1];
            float pg = ga[2][rl][colc] + bsum[2];
            float po = ga[3][rl][colc] + bsum[3];
            float si = 1.f / (1.f + expf(-pi));
            float sf = 1.f / (1.f + expf(-pf));
            float so = 1.f / (1.f + expf(-po));
            float tg = tanhf(pg);
            float cn = sf * creg[q] + si * tg;
            float hn = so * tanhf(cn);
            creg[q] = cn;
            size_t idx = (size_t)r * HH + j;
            bf16 hi = f2bf(hn);
            hob[idx] = hi;
            lob[idx] = f2bf(hn - bf2f(hi));
            if (t == TT - 1) h_fin[idx] = hn;
        }
        if (t == TT - 1) break;

        __syncthreads();
        if (tid == 0)
            __hip_atomic_store(&slots[mi * 32 + cj], t + 1,
                               __ATOMIC_RELEASE, __HIP_MEMORY_SCOPE_AGENT);
        if (tid < 64) {
            const int tgt = t + 1;
            while (true) {
                int v = (lane < 32)
                    ? __hip_atomic_load(&slots[mi * 32 + lane],
                                        __ATOMIC_RELAXED, __HIP_MEMORY_SCOPE_AGENT)
                    : tgt;
                if (__all(v >= tgt)) break;
                __builtin_amdgcn_s_sleep(1);
            }
            __builtin_amdgcn_fence(__ATOMIC_ACQUIRE, "agent");
        }
        __syncthreads();
    }
}

// ---------------------------------------------------------------------------
// FALLBACK-2: per-step kernel (round-3), x gathered from embed
// ---------------------------------------------------------------------------
template<int GATH>
__global__ __launch_bounds__(256) void k_step(
    const bf16* __restrict__ x_bf, const float* __restrict__ embed,
    const int* __restrict__ tok_h, const int* __restrict__ tok_p,
    const bf16* __restrict__ W_ihb, const bf16* __restrict__ W_hhb,
    const float* __restrict__ b_ih, const float* __restrict__ b_hh,
    const bf16* __restrict__ h_hi_in, const bf16* __restrict__ h_lo_in,
    bf16* __restrict__ h_hi_out, bf16* __restrict__ h_lo_out,
    float* __restrict__ c_buf, float* __restrict__ h_fin, int t)
{
    __shared__ float lds[4][64][17];

    const int blk = blockIdx.x;
    const int mi = blk >> 5;
    const int ji = blk & 31;
    const int w    = threadIdx.x >> 6;
    const int lane = threadIdx.x & 63;
    const int l16 = lane & 15;
    const int kq  = lane >> 4;

    const int run = mi >> 1;
    const int s   = run >> 1;
    const int te  = (run & 1) ? (TT - 1 - t) : t;
    const int r0  = mi * 64;

    const bf16*  hhp[4];
    const bf16*  hlp[4];
    const bf16*  xbp[4];
    const float* xfp[4];
#pragma unroll
    for (int mt = 0; mt < 4; ++mt) {
        int r = r0 + mt * 16 + l16;
        hhp[mt] = h_hi_in + (size_t)r * HH;
        hlp[mt] = h_lo_in + (size_t)r * HH;
        int b = r & 127;
        if (GATH) {
            xbp[mt] = x_bf + (((size_t)s * TT + te) * TB + b) * EMB;
        } else {
            int tok = (s ? tok_p : tok_h)[b * TT + te];
            xfp[mt] = embed + (size_t)tok * EMB;
        }
    }

    const int gcol = w * HH + ji * 16 + l16;
    const bf16* wh = W_hhb + (size_t)gcol * HH;
    const bf16* wx = W_ihb + (size_t)gcol * EMB;

    f32x4 acc[4];
#pragma unroll
    for (int mt = 0; mt < 4; ++mt) acc[mt] = (f32x4)0.f;

    for (int kk = 0; kk < HH / 32; ++kk) {
        const int k0 = kk * 32 + kq * 8;
        short8 bwh = *reinterpret_cast<const short8*>(wh + k0);
        short8 bwx = *reinterpret_cast<const short8*>(wx + k0);
#pragma unroll
        for (int mt = 0; mt < 4; ++mt) {
            short8 ax;
            if (GATH) {
                ax = *reinterpret_cast<const short8*>(xbp[mt] + k0);
            } else {
                float4 v0 = *reinterpret_cast<const float4*>(xfp[mt] + k0);
                float4 v1 = *reinterpret_cast<const float4*>(xfp[mt] + k0 + 4);
                ax = pack8(v0, v1);
            }
            short8 ahi = *reinterpret_cast<const short8*>(hhp[mt] + k0);
            short8 alo = *reinterpret_cast<const short8*>(hlp[mt] + k0);
            acc[mt] = __builtin_amdgcn_mfma_f32_16x16x32_bf16(ax,  bwx, acc[mt], 0, 0, 0);
            acc[mt] = __builtin_amdgcn_mfma_f32_16x16x32_bf16(alo, bwh, acc[mt], 0, 0, 0);
            acc[mt] = __builtin_amdgcn_mfma_f32_16x16x32_bf16(ahi, bwh, acc[mt], 0, 0, 0);
        }
    }
#pragma unroll
    for (int mt = 0; mt < 4; ++mt)
#pragma unroll
        for (int q = 0; q < 4; ++q)
            lds[w][mt * 16 + kq * 4 + q][l16] = acc[mt][q];
    __syncthreads();

    const int tid = threadIdx.x;
#pragma unroll
    for (int q = 0; q < 4; ++q) {
        int cell = tid + q * 256;
        int rl  = cell >> 4;
        int col = cell & 15;
        int r = r0 + rl;
        int j = ji * 16 + col;

        float pi = lds[0][rl][col] + b_ih[j]          + b_hh[j];
        float pf = lds[1][rl][col] + b_ih[HH + j]     + b_hh[HH + j];
        float pg = lds[2][rl][col] + b_ih[2 * HH + j] + b_hh[2 * HH + j];
        float po = lds[3][rl][col] + b_ih[3 * HH + j] + b_hh[3 * HH + j];

        float si = 1.f / (1.f + expf(-pi));
        float sf = 1.f / (1.f + expf(-pf));
        float so = 1.f / (1.f + expf(-po));
        float tg = tanhf(pg);

        size_t idx = (size_t)r * HH + j;
        float cn = sf * c_buf[idx] + si * tg;
        float hn = so * tanhf(cn);
        c_buf[idx] = cn;

        bf16 hi = f2bf(hn);
        h_hi_out[idx] = hi;
        h_lo_out[idx] = f2bf(hn - bf2f(hi));
        if (t == TT - 1) h_fin[idx] = hn;
    }
}

// ---------------------------------------------------------------------------
// features [hyp, prem, prem-hyp, hyp*prem] + LayerNorm(4096); block per row
// ---------------------------------------------------------------------------
__global__ __launch_bounds__(256) void k_feat_ln0(
    const float* __restrict__ h_fin, const float* __restrict__ g,
    const float* __restrict__ be, bf16* __restrict__ f_out)
{
    const int b = blockIdx.x;
    const int tid = threadIdx.x;
    float v[16];
    float s = 0.f, sq = 0.f;
#pragma unroll
    for (int i = 0; i < 16; ++i) {
        int e = i * 256 + tid;
        int region = e >> 10;
        int idx = e & 1023;
        int runh = (idx < 512) ? 0 : 1;
        int jj = idx & 511;
        float hy = h_fin[((size_t)(runh * TB + b)) * HH + jj];
        float pr = h_fin[((size_t)((runh + 2) * TB + b)) * HH + jj];
        float val = (region == 0) ? hy : (region == 1) ? pr
                  : (region == 2) ? (pr - hy) : (hy * pr);
        v[i] = val;
        s += val;
        sq += val * val;
    }
    __shared__ float shs[4], shq[4];
    for (int o = 32; o; o >>= 1) { s += __shfl_down(s, o); sq += __shfl_down(sq, o); }
    int w = tid >> 6, lane = tid & 63;
    if (!lane) { shs[w] = s; shq[w] = sq; }
    __syncthreads();
    s  = shs[0] + shs[1] + shs[2] + shs[3];
    sq = shq[0] + shq[1] + shq[2] + shq[3];
    float mean = s / (float)F4;
    float var  = sq / (float)F4 - mean * mean;
    float rstd = rsqrtf(var + 1e-6f);
#pragma unroll
    for (int i = 0; i < 16; ++i) {
        int e = i * 256 + tid;
        float nv = (v[i] - mean) * rstd * g[e] + be[e];
        f_out[(size_t)b * F4 + e] = f2bf(nv);
    }
}

// ---------------------------------------------------------------------------
// split-K MLP partial GEMM
// ---------------------------------------------------------------------------
template<int KTOT, int NCH>
__global__ __launch_bounds__(256) void k_mlp_sk(
    const bf16* __restrict__ A, const float* __restrict__ Bw,
    float* __restrict__ part)
{
    const int KC = KTOT / NCH;
    const int nb = blockIdx.x, mb = blockIdx.y, kc = blockIdx.z;
    const int w    = threadIdx.x >> 6;
    const int lane = threadIdx.x & 63;
    const int wr = w >> 1, wc = w & 1;
    const int l16 = lane & 15;
    const int kq  = lane >> 4;
    const int m0 = mb * 64 + wr * 32;
    const int c0 = nb * 64 + wc * 32;

    f32x4 acc[2][2];
#pragma unroll
    for (int i = 0; i < 2; ++i)
#pragma unroll
        for (int j = 0; j < 2; ++j) acc[i][j] = (f32x4)0.f;

    for (int kk = kc * (KC / 32); kk < (kc + 1) * (KC / 32); ++kk) {
        const int k0 = kk * 32 + kq * 8;
        short8 a[2], bb[2];
#pragma unroll
        for (int i = 0; i < 2; ++i)
            a[i] = *reinterpret_cast<const short8*>(A + (size_t)(m0 + i * 16 + l16) * KTOT + k0);
#pragma unroll
        for (int j = 0; j < 2; ++j) {
            const float* bp = Bw + (size_t)(c0 + j * 16 + l16) * KTOT + k0;
            float4 v0 = *reinterpret_cast<const float4*>(bp);
            float4 v1 = *reinterpret_cast<const float4*>(bp + 4);
            bb[j] = pack8(v0, v1);
        }
#pragma unroll
        for (int i = 0; i < 2; ++i)
#pragma unroll
            for (int j = 0; j < 2; ++j)
                acc[i][j] = __builtin_amdgcn_mfma_f32_16x16x32_bf16(a[i], bb[j], acc[i][j], 0, 0, 0);
    }
#pragma unroll
    for (int i = 0; i < 2; ++i)
#pragma unroll
        for (int j = 0; j < 2; ++j) {
            int gg = c0 + j * 16 + l16;
#pragma unroll
            for (int q = 0; q < 4; ++q) {
                int m = m0 + i * 16 + kq * 4 + q;
                part[((size_t)kc * TB + m) * HD + gg] = acc[i][j][q];
            }
        }
}

// ---------------------------------------------------------------------------
// fused: reduce partials + bias + relu + LayerNorm(1024) -> bf16
// ---------------------------------------------------------------------------
template<int NCH>
__global__ __launch_bounds__(256) void k_redln(
    const float* __restrict__ part, const float* __restrict__ bias,
    const float* __restrict__ g, const float* __restrict__ be,
    bf16* __restrict__ out)
{
    const int b = blockIdx.x;
    const int tid = threadIdx.x;
    float v[4];
    float s = 0.f, sq = 0.f;
#pragma unroll
    for (int i = 0; i < 4; ++i) {
        int e = i * 256 + tid;
        float val = bias[e];
#pragma unroll
        for (int c = 0; c < NCH; ++c) val += part[((size_t)c * TB + b) * HD + e];
        val = fmaxf(val, 0.f);
        v[i] = val; s += val; sq += val * val;
    }
    __shared__ float shs[4], shq[4];
    for (int o = 32; o; o >>= 1) { s += __shfl_down(s, o); sq += __shfl_down(sq, o); }
    int w = tid >> 6, lane = tid & 63;
    if (!lane) { shs[w] = s; shq[w] = sq; }
    __syncthreads();
    s  = shs[0] + shs[1] + shs[2] + shs[3];
    sq = shq[0] + shq[1] + shq[2] + shq[3];
    float mean = s / (float)HD;
    float var  = sq / (float)HD - mean * mean;
    float rstd = rsqrtf(var + 1e-6f);
#pragma unroll
    for (int i = 0; i < 4; ++i) {
        int e = i * 256 + tid;
        out[(size_t)b * HD + e] = f2bf((v[i] - mean) * rstd * g[e] + be[e]);
    }
}

// ---------------------------------------------------------------------------
// fused: reduce + bias + relu + LayerNorm(1024) + out-proj [128,3] (f32 out)
// ---------------------------------------------------------------------------
template<int NCH>
__global__ __launch_bounds__(256) void k_redln_out(
    const float* __restrict__ part, const float* __restrict__ bias,
    const float* __restrict__ g, const float* __restrict__ be,
    const float* __restrict__ Wt, const float* __restrict__ ob,
    float* __restrict__ out)
{
    const int b = blockIdx.x;
    const int tid = threadIdx.x;
    float v[4];
    float s = 0.f, sq = 0.f;
#pragma unroll
    for (int i = 0; i < 4; ++i) {
        int e = i * 256 + tid;
        float val = bias[e];
#pragma unroll
        for (int c = 0; c < NCH; ++c) val += part[((size_t)c * TB + b) * HD + e];
        val = fmaxf(val, 0.f);
        v[i] = val; s += val; sq += val * val;
    }
    __shared__ float shs[4], shq[4];
    for (int o = 32; o; o >>= 1) { s += __shfl_down(s, o); sq += __shfl_down(sq, o); }
    int w = tid >> 6, lane = tid & 63;
    if (!lane) { shs[w] = s; shq[w] = sq; }
    __syncthreads();
    s  = shs[0] + shs[1] + shs[2] + shs[3];
    sq = shq[0] + shq[1] + shq[2] + shq[3];
    float mean = s / (float)HD;
    float var  = sq / (float)HD - mean * mean;
    float rstd = rsqrtf(var + 1e-6f);
    float p0 = 0.f, p1 = 0.f, p2 = 0.f;
#pragma unroll
    for (int i = 0; i < 4; ++i) {
        int e = i * 256 + tid;
        float f = (v[i] - mean) * rstd * g[e] + be[e];
        p0 += f * Wt[e];
        p1 += f * Wt[HD + e];
        p2 += f * Wt[2 * HD + e];
    }
    for (int o = 32; o; o >>= 1) {
        p0 += __shfl_down(p0, o);
        p1 += __shfl_down(p1, o);
        p2 += __shfl_down(p2, o);
    }
    __shared__ float sh[4][3];
    if (!lane) { sh[w][0] = p0; sh[w][1] = p1; sh[w][2] = p2; }
    __syncthreads();
    if (tid < 3)
        out[b * 3 + tid] = sh[0][tid] + sh[1][tid] + sh[2][tid] + sh[3][tid] + ob[tid];
}

// ---------------------------------------------------------------------------
extern "C" void kernel_launch(void* const* d_in, const int* in_sizes, int n_in,
                              void* d_out, int out_size, void* d_ws, size_t ws_size,
                              hipStream_t stream)
{
    const int*   tok_h  = (const int*)  d_in[0];
    const int*   tok_p  = (const int*)  d_in[1];
    const float* embed  = (const float*)d_in[2];
    const float* W_ih   = (const float*)d_in[3];
    const float* W_hh   = (const float*)d_in[4];
    const float* b_ih   = (const float*)d_in[5];
    const float* b_hh   = (const float*)d_in[6];
    const float* mlp1_W = (const float*)d_in[7];
    const float* mlp1_b = (const float*)d_in[8];
    const float* mlp2_W = (const float*)d_in[9];
    const float* mlp2_b = (const float*)d_in[10];
    const float* out_W  = (const float*)d_in[11];
    const float* out_b  = (const float*)d_in[12];
    const float* ln0_g  = (const float*)d_in[13];
    const float* ln0_b  = (const float*)d_in[14];
    const float* ln1_g  = (const float*)d_in[15];
    const float* ln1_b  = (const float*)d_in[16];
    const float* ln2_g  = (const float*)d_in[17];
    const float* ln2_b  = (const float*)d_in[18];

    char* ws = (char*)d_ws;
    size_t off = 0;
    bf16*  f_ln0 = (bf16*)(ws + off);  off += (size_t)TB * F4 * 2;            // 1 MB
    float* part  = (float*)(ws + off); off += (size_t)8 * TB * HD * 4;        // 4 MB
    bf16*  f_ln1 = (bf16*)(ws + off);  off += (size_t)TB * HD * 2;
    float* h_fin = (float*)(ws + off); off += (size_t)NROWS * HH * 4;         // 1 MB
    bf16*  h_hi  = (bf16*)(ws + off);  off += (size_t)2 * NROWS * HH * 2;     // 1 MB
    bf16*  h_lo  = (bf16*)(ws + off);  off += (size_t)2 * NROWS * HH * 2;     // 1 MB
    int*   slots = (int*)(ws + off);   off += 4096;   // flags[256] + xinfo[256]
    float* c_buf = (float*)(ws + off); off += (size_t)NROWS * HH * 4;         // 1 MB
    bf16*  W_ihb = (bf16*)(ws + off);  off += (size_t)G4 * EMB * 2;           // 2 MB
    bf16*  W_hhb = (bf16*)(ws + off);  off += (size_t)G4 * HH * 2;            // 2 MB
    // h_f32 (primary): 2 parities x 512 x 512 f32 = 2 MB, aliases h_hi+h_lo
    float* h_f32 = (float*)h_hi;
    int*   xinfo = slots + 256;
    // big region: UNION of xg (primary, 128 MB) and x_bf (fallback-1, 32 MB)
    bf16*  xg   = (bf16*)(ws + off);
    bf16*  x_bf = (bf16*)(ws + off);
    const size_t need_primary = off + (size_t)2 * TT * TB * G4 * 2;   // +128 MB
    const size_t need_f1      = off + (size_t)2 * TT * TB * EMB * 2;  // +32 MB

    // zero h region + slots/xinfo (contiguous)
    (void)hipMemsetAsync(h_hi, 0, (size_t)4 * NROWS * HH * 2 + 4096, stream);

    const size_t HS = (size_t)NROWS * HH;
    if (ws_size >= need_primary) {
        k_cvt<<<512, 256, 0, stream>>>(W_ih, W_ihb, G4 * EMB / 4);
        k_xproj2<<<dim3(512, 8), 256, 0, stream>>>(tok_h, tok_p, embed, W_ihb,
                                                   b_ih, b_hh, xg);
        void* args[] = {(void*)&xg, (void*)&W_hh, (void*)&b_ih, (void*)&b_hh,
                        (void*)&h_f32, (void*)&h_fin, (void*)&slots, (void*)&xinfo};
        (void)hipLaunchCooperativeKernel((void*)k_persist7, dim3(256), dim3(512),
                                         args, 0, stream);
    } else if (ws_size >= need_f1) {
        k_gather<<<4096, 256, 0, stream>>>(tok_h, tok_p, embed, x_bf);
        void* args[] = {(void*)&x_bf, (void*)&W_ih, (void*)&W_hh,
                        (void*)&b_ih, (void*)&b_hh,
                        (void*)&h_hi, (void*)&h_lo, (void*)&h_fin, (void*)&slots};
        (void)hipLaunchCooperativeKernel((void*)k_persist, dim3(256), dim3(256),
                                         args, 0, stream);
    } else {
        (void)hipMemsetAsync(c_buf, 0, (size_t)NROWS * HH * 4, stream);
        k_cvt<<<512, 256, 0, stream>>>(W_ih, W_ihb, G4 * EMB / 4);
        k_cvt<<<512, 256, 0, stream>>>(W_hh, W_hhb, G4 * HH / 4);
        for (int t = 0; t < TT; ++t) {
            int p = t & 1;
            k_step<0><<<256, 256, 0, stream>>>(x_bf, embed, tok_h, tok_p,
                W_ihb, W_hhb, b_ih, b_hh,
                h_hi + (size_t)p * HS, h_lo + (size_t)p * HS,
                h_hi + (size_t)(p ^ 1) * HS, h_lo + (size_t)(p ^ 1) * HS,
                c_buf, h_fin, t);
        }
    }

    // head (fused)
    k_feat_ln0<<<TB, 256, 0, stream>>>(h_fin, ln0_g, ln0_b, f_ln0);
    k_mlp_sk<F4, 8><<<dim3(16, 2, 8), 256, 0, stream>>>(f_ln0, mlp1_W, part);
    k_redln<8><<<TB, 256, 0, stream>>>(part, mlp1_b, ln1_g, ln1_b, f_ln1);
    k_mlp_sk<HD, 4><<<dim3(16, 2, 4), 256, 0, stream>>>(f_ln1, mlp2_W, part);
    k_redln_out<4><<<TB, 256, 0, stream>>>(part, mlp2_b, ln2_g, ln2_b,
                                           out_W, out_b, (float*)d_out);
}

// Round 11
// 702.738 us; speedup vs baseline: 1.5358x; 1.5358x over previous
//
#include <hip/hip_runtime.h>
#include <hip/hip_bf16.h>

typedef __hip_bfloat16 bf16;
typedef __attribute__((ext_vector_type(8))) short short8;
typedef __attribute__((ext_vector_type(4))) short s16x4;
typedef __attribute__((ext_vector_type(4))) float f32x4;
typedef __attribute__((ext_vector_type(2))) float f32x2;

#define TB 128      // batch
#define TT 128      // time
#define EMB 512     // embed dim
#define HH 512      // per-direction hidden
#define G4 2048     // 4*HH gate dim
#define NROWS 512   // 4 runs * 128 batch
#define F4 4096     // feature dim
#define HD 1024     // mlp hidden

__device__ __forceinline__ bf16 f2bf(float x){ return __float2bfloat16(x); }
__device__ __forceinline__ float bf2f(bf16 x){ return __bfloat162float(x); }

// fast gates: v_exp_f32 + v_rcp_f32; saturate cleanly (rcp(inf)=0), no NaN
__device__ __forceinline__ float fsigm(float x){
    return __builtin_amdgcn_rcpf(1.f + __builtin_amdgcn_exp2f(-1.44269504089f * x));
}
__device__ __forceinline__ float ftanh(float x){
    float t = __builtin_amdgcn_exp2f(2.88539008178f * x);
    return 1.f - 2.f * __builtin_amdgcn_rcpf(t + 1.f);
}

__device__ __forceinline__ short8 pack8(float4 a, float4 b){
    short8 r;
    r[0] = (short)__bfloat16_as_ushort(f2bf(a.x));
    r[1] = (short)__bfloat16_as_ushort(f2bf(a.y));
    r[2] = (short)__bfloat16_as_ushort(f2bf(a.z));
    r[3] = (short)__bfloat16_as_ushort(f2bf(a.w));
    r[4] = (short)__bfloat16_as_ushort(f2bf(b.x));
    r[5] = (short)__bfloat16_as_ushort(f2bf(b.y));
    r[6] = (short)__bfloat16_as_ushort(f2bf(b.z));
    r[7] = (short)__bfloat16_as_ushort(f2bf(b.w));
    return r;
}

// ---------------------------------------------------------------------------
// f32 -> bf16 conversion
// ---------------------------------------------------------------------------
__global__ __launch_bounds__(256) void k_cvt(const float* __restrict__ src,
                                             bf16* __restrict__ dst, int n4)
{
    for (int i = blockIdx.x * 256 + threadIdx.x; i < n4; i += gridDim.x * 256) {
        float4 v = reinterpret_cast<const float4*>(src)[i];
        s16x4 o;
        o[0] = (short)__bfloat16_as_ushort(f2bf(v.x));
        o[1] = (short)__bfloat16_as_ushort(f2bf(v.y));
        o[2] = (short)__bfloat16_as_ushort(f2bf(v.z));
        o[3] = (short)__bfloat16_as_ushort(f2bf(v.w));
        reinterpret_cast<s16x4*>(dst)[i] = o;
    }
}

// ---------------------------------------------------------------------------
// Gather embed rows to bf16 x_bf[s][t][b][e]  (fallback-1 path only)
// ---------------------------------------------------------------------------
__global__ __launch_bounds__(256) void k_gather(
    const int* __restrict__ tok_h, const int* __restrict__ tok_p,
    const float* __restrict__ embed, bf16* __restrict__ x_bf)
{
    const int total4 = 2 * TT * TB * (EMB / 4);
    for (int g = blockIdx.x * 256 + threadIdx.x; g < total4; g += gridDim.x * 256) {
        int e4 = g & (EMB / 4 - 1);
        int b  = (g >> 7) & 127;
        int t  = (g >> 14) & 127;
        int s  = g >> 21;
        int tok = (s ? tok_p : tok_h)[b * TT + t];
        float4 v = reinterpret_cast<const float4*>(embed + (size_t)tok * EMB)[e4];
        s16x4 o;
        o[0] = (short)__bfloat16_as_ushort(f2bf(v.x));
        o[1] = (short)__bfloat16_as_ushort(f2bf(v.y));
        o[2] = (short)__bfloat16_as_ushort(f2bf(v.z));
        o[3] = (short)__bfloat16_as_ushort(f2bf(v.w));
        reinterpret_cast<s16x4*>(x_bf + (((size_t)s * TT + t) * TB + b) * EMB)[e4] = o;
    }
}

// ---------------------------------------------------------------------------
// xg[m][g] = embed[tok(m)] . W_ih[g] + b_ih[g] + b_hh[g]   (bf16 out)
// grid (512, 8): mb fastest (same-A blocks co-XCD). B = pre-cvt bf16 W_ihb.
// ---------------------------------------------------------------------------
__global__ __launch_bounds__(256) void k_xproj2(
    const int* __restrict__ tok_h, const int* __restrict__ tok_p,
    const float* __restrict__ embed, const bf16* __restrict__ W_ihb,
    const float* __restrict__ b_ih, const float* __restrict__ b_hh,
    bf16* __restrict__ xg)
{
    __shared__ __align__(16) short As[64][512];
    const int mb = blockIdx.x;      // 0..511 (64-row slabs)  [fastest dim]
    const int nb = blockIdx.y;      // 0..7 (256-col slabs)
    const int tid = threadIdx.x;
    const int w = tid >> 6, lane = tid & 63, l16 = lane & 15, kq = lane >> 4;
    const int m0 = mb * 64;
    const int s  = m0 >> 14;
    const int tt = (m0 >> 7) & 127;
    const int bbase = m0 & 127;     // 0 or 64
    const int* tp = s ? tok_p : tok_h;

#pragma unroll
    for (int it = 0; it < 16; ++it) {
        int idx = it * 256 + tid;
        int row = idx >> 6;
        int ch  = idx & 63;
        int tok = tp[(bbase + row) * TT + tt];
        const float* er = embed + (size_t)tok * EMB + ch * 8;
        float4 v0 = *(const float4*)er;
        float4 v1 = *(const float4*)(er + 4);
        *(short8*)&As[row][(ch ^ (row & 7)) * 8] = pack8(v0, v1);
    }
    __syncthreads();

    const int c0 = nb * 256 + w * 64;
    f32x4 acc[4][4];
#pragma unroll
    for (int mt = 0; mt < 4; ++mt)
#pragma unroll
        for (int nt = 0; nt < 4; ++nt) acc[mt][nt] = (f32x4)0.f;

    for (int kk = 0; kk < 16; ++kk) {
        short8 bfr[4];
#pragma unroll
        for (int nt = 0; nt < 4; ++nt)
            bfr[nt] = *(const short8*)(W_ihb + (size_t)(c0 + nt * 16 + l16) * EMB + kk * 32 + kq * 8);
#pragma unroll
        for (int mt = 0; mt < 4; ++mt) {
            int row = mt * 16 + l16;
            short8 a = *(const short8*)&As[row][(((kk * 4 + kq) ^ (row & 7)) * 8)];
#pragma unroll
            for (int nt = 0; nt < 4; ++nt)
                acc[mt][nt] = __builtin_amdgcn_mfma_f32_16x16x32_bf16(a, bfr[nt], acc[mt][nt], 0, 0, 0);
        }
    }
#pragma unroll
    for (int nt = 0; nt < 4; ++nt) {
        int col = c0 + nt * 16 + l16;
        float bias = b_ih[col] + b_hh[col];
#pragma unroll
        for (int mt = 0; mt < 4; ++mt)
#pragma unroll
            for (int q = 0; q < 4; ++q) {
                int m = m0 + mt * 16 + kq * 4 + q;
                xg[(size_t)m * G4 + col] = f2bf(acc[mt][nt][q] + bias);
            }
    }
}

// ---------------------------------------------------------------------------
// PERSISTENT LSTM v8 (cooperative) = round-9 v6 structure (proven 552 us)
// + fast gates (round-10, -23% VALU) + ga pad 18.
// h data: local-XCD L2 (sc0) when rgroup co-located, MALL (sc0 sc1) else.
// Flags: ALWAYS agent atomics (round-10 lesson: sc0 flag polling reads
// stale L1-resident lines -> +2.6 us/step; h data is safe only because its
// 32KB/step thrashes L1).
// ---------------------------------------------------------------------------
__global__ __launch_bounds__(512, 1) void k_persist8(
    const bf16* __restrict__ xg, const float* __restrict__ W_hh,
    const float* __restrict__ b_ih, const float* __restrict__ b_hh,
    float* __restrict__ h_f32, float* __restrict__ h_fin,
    int* __restrict__ slots, int* __restrict__ xinfo)
{
    __shared__ __align__(16) short hstage[2][16][512];   // 32 KB (hi,lo)
    __shared__ float ga[16][16][18];                     // 18 KB

    const int tid = threadIdx.x;
    const int bid = blockIdx.x;
    const int rg = bid & 31;          // rgroup (16 rows); bid%8 == rg%8
    const int cb = bid >> 5;          // 0..7 col-block (64 h-cols)
    const int w = tid >> 6, lane = tid & 63, l16 = lane & 15, kq = lane >> 4;
    const int j0 = cb * 64;
    const int r0 = rg * 16;
    const int run = rg >> 3;          // 0 hypF, 1 hypB, 2 premF, 3 premB
    const int s = run >> 1, dirb = run & 1;
    const int b0 = (rg & 7) * 16;

    // ---- co-location detection (safe under cooperative residency) ----
    bool mall = false;
    {
        int myx;
        asm volatile("s_getreg_b32 %0, hwreg(HW_REG_XCC_ID)" : "=s"(myx));
        if (tid == 0)
            __hip_atomic_store(&xinfo[bid], (myx & 15) + 1,
                               __ATOMIC_RELAXED, __HIP_MEMORY_SCOPE_AGENT);
        int v0 = 0;
        for (int c = 0; c < 8; ++c) {
            int v;
            do {
                v = __hip_atomic_load(&xinfo[c * 32 + rg],
                                      __ATOMIC_RELAXED, __HIP_MEMORY_SCOPE_AGENT);
                if (!v) __builtin_amdgcn_s_sleep(2);
            } while (!v);
            if (c == 0) v0 = v;
            else if (v != v0) mall = true;
        }
    }

    // ---- W_hh register frags: wave w owns ntiles 2w, 2w+1 ----
    short8 Bf[2][16];
#pragma unroll
    for (int nt = 0; nt < 2; ++nt) {
        int n = 2 * w + nt;
        int gcol = (n >> 2) * HH + j0 + (n & 3) * 16 + l16;
        const float* wr = W_hh + (size_t)gcol * HH;
#pragma unroll
        for (int kk = 0; kk < 16; ++kk) {
            float4 v0 = *(const float4*)(wr + kk * 32 + kq * 8);
            float4 v1 = *(const float4*)(wr + kk * 32 + kq * 8 + 4);
            Bf[nt][kk] = pack8(v0, v1);
        }
    }

    const int urow = tid >> 5;        // 0..15
    const int jseg = tid & 31;        // 16-f32 segment / 2-cell col pair
    float bsum[2][4];
#pragma unroll
    for (int e = 0; e < 2; ++e)
#pragma unroll
        for (int g = 0; g < 4; ++g) {
            int j = g * HH + j0 + jseg * 2 + e;
            bsum[e][g] = b_ih[j] + b_hh[j];
        }
    float creg[2] = {0.f, 0.f};
    const size_t HSF = (size_t)NROWS * HH;

    // xg element offsets for this thread's 8 acc-init values
    int rowoff[8];
#pragma unroll
    for (int nt = 0; nt < 2; ++nt) {
        int n = 2 * w + nt;
        int gcol = (n >> 2) * HH + j0 + (n & 3) * 16 + l16;
#pragma unroll
        for (int q = 0; q < 4; ++q)
            rowoff[nt * 4 + q] = (b0 + kq * 4 + q) * G4 + gcol;
    }

    // prologue: xg prefetch for t=0 (normal cached loads)
    unsigned xp[8];
    {
        int te0 = dirb ? (TT - 1) : 0;
        const bf16* xr = xg + ((size_t)(s * TT + te0) * TB) * G4;
#pragma unroll
        for (int i = 0; i < 8; ++i)
            xp[i] = (unsigned)__bfloat16_as_ushort(xr[rowoff[i]]);
    }

    for (int t = 0; t < TT; ++t) {
        const int p = t & 1;

        // ---- h loads: local-XCD L2 (sc0) if co-located, else MALL ----
        f32x4 hv[4];
        {
            unsigned long long a = (unsigned long long)(
                h_f32 + (size_t)p * HSF + (size_t)(r0 + urow) * HH + jseg * 16);
            if (mall) {
#pragma unroll
                for (int i = 0; i < 4; ++i)
                    asm volatile("global_load_dwordx4 %0, %1, off sc0 sc1"
                                 : "=v"(hv[i]) : "v"(a + i * 16));
            } else {
#pragma unroll
                for (int i = 0; i < 4; ++i)
                    asm volatile("global_load_dwordx4 %0, %1, off sc0"
                                 : "=v"(hv[i]) : "v"(a + i * 16));
            }
        }
        asm volatile("s_waitcnt vmcnt(0)" ::: "memory");
        __builtin_amdgcn_sched_barrier(0);

        // ---- stage hi/lo to LDS (XOR-swizzled) ----
#pragma unroll
        for (int half = 0; half < 2; ++half) {
            short8 hi, lo;
#pragma unroll
            for (int i2 = 0; i2 < 8; ++i2) {
                float v = hv[half * 2 + (i2 >> 2)][i2 & 3];
                bf16 hb = f2bf(v);
                hi[i2] = (short)__bfloat16_as_ushort(hb);
                lo[i2] = (short)__bfloat16_as_ushort(f2bf(v - bf2f(hb)));
            }
            int ch = (2 * jseg + half) ^ (urow & 7);
            *(short8*)&hstage[0][urow][ch * 8] = hi;
            *(short8*)&hstage[1][urow][ch * 8] = lo;
        }

        // acc init from prefetched xg bits (bf16 -> f32 is a shift)
        f32x4 acc[2];
#pragma unroll
        for (int nt = 0; nt < 2; ++nt)
#pragma unroll
            for (int q = 0; q < 4; ++q)
                acc[nt][q] = __uint_as_float(xp[nt * 4 + q] << 16);

        __syncthreads();   // sync #1: hstage ready

        // ---- MFMA: gates += (h_lo + h_hi) @ W_hh^T ----
#pragma unroll
        for (int kk = 0; kk < 16; ++kk) {
            int ch = ((kk * 4 + kq) ^ (l16 & 7)) * 8;
            short8 ahi = *(const short8*)&hstage[0][l16][ch];
            short8 alo = *(const short8*)&hstage[1][l16][ch];
#pragma unroll
            for (int nt = 0; nt < 2; ++nt) {
                acc[nt] = __builtin_amdgcn_mfma_f32_16x16x32_bf16(alo, Bf[nt][kk], acc[nt], 0, 0, 0);
                acc[nt] = __builtin_amdgcn_mfma_f32_16x16x32_bf16(ahi, Bf[nt][kk], acc[nt], 0, 0, 0);
            }
        }

        // ---- gate exchange ----
#pragma unroll
        for (int nt = 0; nt < 2; ++nt)
#pragma unroll
            for (int q = 0; q < 4; ++q)
                ga[2 * w + nt][kq * 4 + q][l16] = acc[nt][q];
        __syncthreads();   // sync #2: ga ready

        // ---- cell update (fast gates) ----
        float hn2[2];
#pragma unroll
        for (int e = 0; e < 2; ++e) {
            int jc = jseg * 2 + e;
            int sub = jc >> 4, c15 = jc & 15;
            float pi = ga[0 + sub][urow][c15]  + bsum[e][0];
            float pf = ga[4 + sub][urow][c15]  + bsum[e][1];
            float pg = ga[8 + sub][urow][c15]  + bsum[e][2];
            float po = ga[12 + sub][urow][c15] + bsum[e][3];
            float cn = fsigm(pf) * creg[e] + fsigm(pi) * ftanh(pg);
            float hn = fsigm(po) * ftanh(cn);
            creg[e] = cn;
            hn2[e] = hn;
        }
        // h store — first vmem op after full drain
        {
            unsigned long long a = (unsigned long long)(
                h_f32 + (size_t)(p ^ 1) * HSF + (size_t)(r0 + urow) * HH + j0 + jseg * 2);
            f32x2 val; val[0] = hn2[0]; val[1] = hn2[1];
            if (mall)
                asm volatile("global_store_dwordx2 %0, %1, off sc0 sc1"
                             :: "v"(a), "v"(val) : "memory");
            else
                asm volatile("global_store_dwordx2 %0, %1, off sc0"
                             :: "v"(a), "v"(val) : "memory");
        }
        if (t == TT - 1) {
            size_t fb = (size_t)(r0 + urow) * HH + j0 + jseg * 2;
            h_fin[fb] = hn2[0];
            h_fin[fb + 1] = hn2[1];
            break;
        }

        // ---- xg prefetch for t+1 (issued after store; vmcnt(8) => store done)
        {
            int ten = dirb ? (TT - 2 - t) : (t + 1);
            const bf16* xrn = xg + ((size_t)(s * TT + ten) * TB) * G4;
#pragma unroll
            for (int i = 0; i < 8; ++i)
                asm volatile("global_load_ushort %0, %1, off"
                             : "=v"(xp[i])
                             : "v"((unsigned long long)(xrn + rowoff[i])));
        }
        asm volatile("s_waitcnt vmcnt(8)" ::: "memory");  // h store drained
        __syncthreads();   // sync #3: all waves' stores drained
        if (tid == 0)
            __hip_atomic_store(&slots[rg * 8 + cb], t + 1,
                               __ATOMIC_RELAXED, __HIP_MEMORY_SCOPE_AGENT);
        // ---- all-wave poll via AGENT atomics (proven round-9 path) ----
        {
            int sidx = rg * 8 + (lane & 7);
            while (true) {
                int v = (lane < 8)
                    ? __hip_atomic_load(&slots[sidx],
                                        __ATOMIC_RELAXED, __HIP_MEMORY_SCOPE_AGENT)
                    : 0x7fffffff;
                if (__all(v >= t + 1)) break;
                __builtin_amdgcn_s_sleep(1);
            }
        }
    }
}

// ---------------------------------------------------------------------------
// FALLBACK-1: cooperative persistent kernel (round-4 proven)
// ---------------------------------------------------------------------------
__global__ __launch_bounds__(256) void k_persist(
    const bf16* __restrict__ x_bf,
    const float* __restrict__ W_ih, const float* __restrict__ W_hh,
    const float* __restrict__ b_ih, const float* __restrict__ b_hh,
    bf16* __restrict__ h_hi, bf16* __restrict__ h_lo,
    float* __restrict__ h_fin, int* slots)
{
    __shared__ short Wl[4 * 16 * 16 * 64];
    __shared__ float ga[4][64][17];

    const int tid = threadIdx.x;
    const int bx  = blockIdx.x;
    const int mi  = bx & 7;
    const int cj  = bx >> 3;
    const int w    = tid >> 6;
    const int lane = tid & 63;
    const int l16 = lane & 15;
    const int kq  = lane >> 4;
    const int j0  = cj * 16;
    const int r0  = mi * 64;
    const int run = mi >> 1;
    const int s   = run >> 1;
    const int dirb = run & 1;

    {
        int gc  = tid >> 2;
        int g   = gc >> 4, c = gc & 15;
        int kq4 = tid & 3;
        const float* wxr = W_ih + (size_t)(g * HH + j0 + c) * EMB;
        const float* whr = W_hh + (size_t)(g * HH + j0 + c) * HH;
        for (int kb = 0; kb < 16; ++kb) {
            int k  = kq4 * 128 + kb * 8;
            int kk = k >> 5;
            int eq = (k >> 3) & 3;
            float4 x0 = *(const float4*)(wxr + k);
            float4 x1 = *(const float4*)(wxr + k + 4);
            float4 h0 = *(const float4*)(whr + k);
            float4 h1 = *(const float4*)(whr + k + 4);
            int base = ((g * 16 + kk) * 16 + c) * 64;
            int sx = eq ^ (c & 7);
            int sh = (eq + 4) ^ (c & 7);
            *(short8*)&Wl[base + sx * 8] = pack8(x0, x1);
            *(short8*)&Wl[base + sh * 8] = pack8(h0, h1);
        }
    }

    float bsum[4];
    {
        int j = j0 + (tid & 15);
#pragma unroll
        for (int g = 0; g < 4; ++g) bsum[g] = b_ih[g * HH + j] + b_hh[g * HH + j];
    }
    float creg[4] = {0.f, 0.f, 0.f, 0.f};
    __syncthreads();

    const size_t HS = (size_t)NROWS * HH;
    for (int t = 0; t < TT; ++t) {
        const int p  = t & 1;
        const int te = dirb ? (TT - 1 - t) : t;
        const bf16* hb = h_hi + (size_t)p * HS;
        const bf16* lb = h_lo + (size_t)p * HS;
        const bf16* xr0 = x_bf + ((size_t)(s * TT + te) * TB) * EMB;

        f32x4 acc[4];
#pragma unroll
        for (int mt = 0; mt < 4; ++mt) acc[mt] = (f32x4)0.f;

        const bf16 *ph[4], *pl[4], *px[4];
#pragma unroll
        for (int mt = 0; mt < 4; ++mt) {
            int r = r0 + mt * 16 + l16;
            ph[mt] = hb + (size_t)r * HH;
            pl[mt] = lb + (size_t)r * HH;
            px[mt] = xr0 + (size_t)(r & 127) * EMB;
        }

        for (int kk = 0; kk < 16; ++kk) {
            int cbse = ((w * 16 + kk) * 16 + l16) * 64;
            short8 fx = *(const short8*)&Wl[cbse + ((kq ^ (lane & 7)) * 8)];
            short8 fh = *(const short8*)&Wl[cbse + (((kq + 4) ^ (lane & 7)) * 8)];
            int k0 = kk * 32 + kq * 8;
#pragma unroll
            for (int mt = 0; mt < 4; ++mt) {
                short8 ax  = *(const short8*)(px[mt] + k0);
                short8 ahi = *(const short8*)(ph[mt] + k0);
                short8 alo = *(const short8*)(pl[mt] + k0);
                acc[mt] = __builtin_amdgcn_mfma_f32_16x16x32_bf16(ax,  fx, acc[mt], 0, 0, 0);
                acc[mt] = __builtin_amdgcn_mfma_f32_16x16x32_bf16(alo, fh, acc[mt], 0, 0, 0);
                acc[mt] = __builtin_amdgcn_mfma_f32_16x16x32_bf16(ahi, fh, acc[mt], 0, 0, 0);
            }
        }
#pragma unroll
        for (int mt = 0; mt < 4; ++mt)
#pragma unroll
            for (int q = 0; q < 4; ++q)
                ga[w][mt * 16 + kq * 4 + q][l16] = acc[mt][q];
        __syncthreads();

        bf16* hob = h_hi + (size_t)(p ^ 1) * HS;
        bf16* lob = h_lo + (size_t)(p ^ 1) * HS;
        const int colc = tid & 15;
        const int j = j0 + colc;
#pragma unroll
        for (int q = 0; q < 4; ++q) {
            int rl = (tid >> 4) + q * 16;
            int r  = r0 + rl;
            float pi = ga[0][rl][colc] + bsum[0];
            float pf = ga[1][rl][colc] + bsum[1];
            float pg = ga[2][rl][colc] + bsum[2];
            float po = ga[3][rl][colc] + bsum[3];
            float si = 1.f / (1.f + expf(-pi));
            float sf = 1.f / (1.f + expf(-pf));
            float so = 1.f / (1.f + expf(-po));
            float tg = tanhf(pg);
            float cn = sf * creg[q] + si * tg;
            float hn = so * tanhf(cn);
            creg[q] = cn;
            size_t idx = (size_t)r * HH + j;
            bf16 hi = f2bf(hn);
            hob[idx] = hi;
            lob[idx] = f2bf(hn - bf2f(hi));
            if (t == TT - 1) h_fin[idx] = hn;
        }
        if (t == TT - 1) break;

        __syncthreads();
        if (tid == 0)
            __hip_atomic_store(&slots[mi * 32 + cj], t + 1,
                               __ATOMIC_RELEASE, __HIP_MEMORY_SCOPE_AGENT);
        if (tid < 64) {
            const int tgt = t + 1;
            while (true) {
                int v = (lane < 32)
                    ? __hip_atomic_load(&slots[mi * 32 + lane],
                                        __ATOMIC_RELAXED, __HIP_MEMORY_SCOPE_AGENT)
                    : tgt;
                if (__all(v >= tgt)) break;
                __builtin_amdgcn_s_sleep(1);
            }
            __builtin_amdgcn_fence(__ATOMIC_ACQUIRE, "agent");
        }
        __syncthreads();
    }
}

// ---------------------------------------------------------------------------
// FALLBACK-2: per-step kernel (round-3), x gathered from embed
// ---------------------------------------------------------------------------
template<int GATH>
__global__ __launch_bounds__(256) void k_step(
    const bf16* __restrict__ x_bf, const float* __restrict__ embed,
    const int* __restrict__ tok_h, const int* __restrict__ tok_p,
    const bf16* __restrict__ W_ihb, const bf16* __restrict__ W_hhb,
    const float* __restrict__ b_ih, const float* __restrict__ b_hh,
    const bf16* __restrict__ h_hi_in, const bf16* __restrict__ h_lo_in,
    bf16* __restrict__ h_hi_out, bf16* __restrict__ h_lo_out,
    float* __restrict__ c_buf, float* __restrict__ h_fin, int t)
{
    __shared__ float lds[4][64][17];

    const int blk = blockIdx.x;
    const int mi = blk >> 5;
    const int ji = blk & 31;
    const int w    = threadIdx.x >> 6;
    const int lane = threadIdx.x & 63;
    const int l16 = lane & 15;
    const int kq  = lane >> 4;

    const int run = mi >> 1;
    const int s   = run >> 1;
    const int te  = (run & 1) ? (TT - 1 - t) : t;
    const int r0  = mi * 64;

    const bf16*  hhp[4];
    const bf16*  hlp[4];
    const bf16*  xbp[4];
    const float* xfp[4];
#pragma unroll
    for (int mt = 0; mt < 4; ++mt) {
        int r = r0 + mt * 16 + l16;
        hhp[mt] = h_hi_in + (size_t)r * HH;
        hlp[mt] = h_lo_in + (size_t)r * HH;
        int b = r & 127;
        if (GATH) {
            xbp[mt] = x_bf + (((size_t)s * TT + te) * TB + b) * EMB;
        } else {
            int tok = (s ? tok_p : tok_h)[b * TT + te];
            xfp[mt] = embed + (size_t)tok * EMB;
        }
    }

    const int gcol = w * HH + ji * 16 + l16;
    const bf16* wh = W_hhb + (size_t)gcol * HH;
    const bf16* wx = W_ihb + (size_t)gcol * EMB;

    f32x4 acc[4];
#pragma unroll
    for (int mt = 0; mt < 4; ++mt) acc[mt] = (f32x4)0.f;

    for (int kk = 0; kk < HH / 32; ++kk) {
        const int k0 = kk * 32 + kq * 8;
        short8 bwh = *reinterpret_cast<const short8*>(wh + k0);
        short8 bwx = *reinterpret_cast<const short8*>(wx + k0);
#pragma unroll
        for (int mt = 0; mt < 4; ++mt) {
            short8 ax;
            if (GATH) {
                ax = *reinterpret_cast<const short8*>(xbp[mt] + k0);
            } else {
                float4 v0 = *reinterpret_cast<const float4*>(xfp[mt] + k0);
                float4 v1 = *reinterpret_cast<const float4*>(xfp[mt] + k0 + 4);
                ax = pack8(v0, v1);
            }
            short8 ahi = *reinterpret_cast<const short8*>(hhp[mt] + k0);
            short8 alo = *reinterpret_cast<const short8*>(hlp[mt] + k0);
            acc[mt] = __builtin_amdgcn_mfma_f32_16x16x32_bf16(ax,  bwx, acc[mt], 0, 0, 0);
            acc[mt] = __builtin_amdgcn_mfma_f32_16x16x32_bf16(alo, bwh, acc[mt], 0, 0, 0);
            acc[mt] = __builtin_amdgcn_mfma_f32_16x16x32_bf16(ahi, bwh, acc[mt], 0, 0, 0);
        }
    }
#pragma unroll
    for (int mt = 0; mt < 4; ++mt)
#pragma unroll
        for (int q = 0; q < 4; ++q)
            lds[w][mt * 16 + kq * 4 + q][l16] = acc[mt][q];
    __syncthreads();

    const int tid = threadIdx.x;
#pragma unroll
    for (int q = 0; q < 4; ++q) {
        int cell = tid + q * 256;
        int rl  = cell >> 4;
        int col = cell & 15;
        int r = r0 + rl;
        int j = ji * 16 + col;

        float pi = lds[0][rl][col] + b_ih[j]          + b_hh[j];
        float pf = lds[1][rl][col] + b_ih[HH + j]     + b_hh[HH + j];
        float pg = lds[2][rl][col] + b_ih[2 * HH + j] + b_hh[2 * HH + j];
        float po = lds[3][rl][col] + b_ih[3 * HH + j] + b_hh[3 * HH + j];

        float si = 1.f / (1.f + expf(-pi));
        float sf = 1.f / (1.f + expf(-pf));
        float so = 1.f / (1.f + expf(-po));
        float tg = tanhf(pg);

        size_t idx = (size_t)r * HH + j;
        float cn = sf * c_buf[idx] + si * tg;
        float hn = so * tanhf(cn);
        c_buf[idx] = cn;

        bf16 hi = f2bf(hn);
        h_hi_out[idx] = hi;
        h_lo_out[idx] = f2bf(hn - bf2f(hi));
        if (t == TT - 1) h_fin[idx] = hn;
    }
}

// ---------------------------------------------------------------------------
// features [hyp, prem, prem-hyp, hyp*prem] + LayerNorm(4096); block per row
// ---------------------------------------------------------------------------
__global__ __launch_bounds__(256) void k_feat_ln0(
    const float* __restrict__ h_fin, const float* __restrict__ g,
    const float* __restrict__ be, bf16* __restrict__ f_out)
{
    const int b = blockIdx.x;
    const int tid = threadIdx.x;
    float v[16];
    float s = 0.f, sq = 0.f;
#pragma unroll
    for (int i = 0; i < 16; ++i) {
        int e = i * 256 + tid;
        int region = e >> 10;
        int idx = e & 1023;
        int runh = (idx < 512) ? 0 : 1;
        int jj = idx & 511;
        float hy = h_fin[((size_t)(runh * TB + b)) * HH + jj];
        float pr = h_fin[((size_t)((runh + 2) * TB + b)) * HH + jj];
        float val = (region == 0) ? hy : (region == 1) ? pr
                  : (region == 2) ? (pr - hy) : (hy * pr);
        v[i] = val;
        s += val;
        sq += val * val;
    }
    __shared__ float shs[4], shq[4];
    for (int o = 32; o; o >>= 1) { s += __shfl_down(s, o); sq += __shfl_down(sq, o); }
    int w = tid >> 6, lane = tid & 63;
    if (!lane) { shs[w] = s; shq[w] = sq; }
    __syncthreads();
    s  = shs[0] + shs[1] + shs[2] + shs[3];
    sq = shq[0] + shq[1] + shq[2] + shq[3];
    float mean = s / (float)F4;
    float var  = sq / (float)F4 - mean * mean;
    float rstd = rsqrtf(var + 1e-6f);
#pragma unroll
    for (int i = 0; i < 16; ++i) {
        int e = i * 256 + tid;
        float nv = (v[i] - mean) * rstd * g[e] + be[e];
        f_out[(size_t)b * F4 + e] = f2bf(nv);
    }
}

// ---------------------------------------------------------------------------
// split-K MLP partial GEMM
// ---------------------------------------------------------------------------
template<int KTOT, int NCH>
__global__ __launch_bounds__(256) void k_mlp_sk(
    const bf16* __restrict__ A, const float* __restrict__ Bw,
    float* __restrict__ part)
{
    const int KC = KTOT / NCH;
    const int nb = blockIdx.x, mb = blockIdx.y, kc = blockIdx.z;
    const int w    = threadIdx.x >> 6;
    const int lane = threadIdx.x & 63;
    const int wr = w >> 1, wc = w & 1;
    const int l16 = lane & 15;
    const int kq  = lane >> 4;
    const int m0 = mb * 64 + wr * 32;
    const int c0 = nb * 64 + wc * 32;

    f32x4 acc[2][2];
#pragma unroll
    for (int i = 0; i < 2; ++i)
#pragma unroll
        for (int j = 0; j < 2; ++j) acc[i][j] = (f32x4)0.f;

    for (int kk = kc * (KC / 32); kk < (kc + 1) * (KC / 32); ++kk) {
        const int k0 = kk * 32 + kq * 8;
        short8 a[2], bb[2];
#pragma unroll
        for (int i = 0; i < 2; ++i)
            a[i] = *reinterpret_cast<const short8*>(A + (size_t)(m0 + i * 16 + l16) * KTOT + k0);
#pragma unroll
        for (int j = 0; j < 2; ++j) {
            const float* bp = Bw + (size_t)(c0 + j * 16 + l16) * KTOT + k0;
            float4 v0 = *reinterpret_cast<const float4*>(bp);
            float4 v1 = *reinterpret_cast<const float4*>(bp + 4);
            bb[j] = pack8(v0, v1);
        }
#pragma unroll
        for (int i = 0; i < 2; ++i)
#pragma unroll
            for (int j = 0; j < 2; ++j)
                acc[i][j] = __builtin_amdgcn_mfma_f32_16x16x32_bf16(a[i], bb[j], acc[i][j], 0, 0, 0);
    }
#pragma unroll
    for (int i = 0; i < 2; ++i)
#pragma unroll
        for (int j = 0; j < 2; ++j) {
            int gg = c0 + j * 16 + l16;
#pragma unroll
            for (int q = 0; q < 4; ++q) {
                int m = m0 + i * 16 + kq * 4 + q;
                part[((size_t)kc * TB + m) * HD + gg] = acc[i][j][q];
            }
        }
}

// ---------------------------------------------------------------------------
// fused: reduce partials + bias + relu + LayerNorm(1024) -> bf16
// ---------------------------------------------------------------------------
template<int NCH>
__global__ __launch_bounds__(256) void k_redln(
    const float* __restrict__ part, const float* __restrict__ bias,
    const float* __restrict__ g, const float* __restrict__ be,
    bf16* __restrict__ out)
{
    const int b = blockIdx.x;
    const int tid = threadIdx.x;
    float v[4];
    float s = 0.f, sq = 0.f;
#pragma unroll
    for (int i = 0; i < 4; ++i) {
        int e = i * 256 + tid;
        float val = bias[e];
#pragma unroll
        for (int c = 0; c < NCH; ++c) val += part[((size_t)c * TB + b) * HD + e];
        val = fmaxf(val, 0.f);
        v[i] = val; s += val; sq += val * val;
    }
    __shared__ float shs[4], shq[4];
    for (int o = 32; o; o >>= 1) { s += __shfl_down(s, o); sq += __shfl_down(sq, o); }
    int w = tid >> 6, lane = tid & 63;
    if (!lane) { shs[w] = s; shq[w] = sq; }
    __syncthreads();
    s  = shs[0] + shs[1] + shs[2] + shs[3];
    sq = shq[0] + shq[1] + shq[2] + shq[3];
    float mean = s / (float)HD;
    float var  = sq / (float)HD - mean * mean;
    float rstd = rsqrtf(var + 1e-6f);
#pragma unroll
    for (int i = 0; i < 4; ++i) {
        int e = i * 256 + tid;
        out[(size_t)b * HD + e] = f2bf((v[i] - mean) * rstd * g[e] + be[e]);
    }
}

// ---------------------------------------------------------------------------
// fused: reduce + bias + relu + LayerNorm(1024) + out-proj [128,3] (f32 out)
// ---------------------------------------------------------------------------
template<int NCH>
__global__ __launch_bounds__(256) void k_redln_out(
    const float* __restrict__ part, const float* __restrict__ bias,
    const float* __restrict__ g, const float* __restrict__ be,
    const float* __restrict__ Wt, const float* __restrict__ ob,
    float* __restrict__ out)
{
    const int b = blockIdx.x;
    const int tid = threadIdx.x;
    float v[4];
    float s = 0.f, sq = 0.f;
#pragma unroll
    for (int i = 0; i < 4; ++i) {
        int e = i * 256 + tid;
        float val = bias[e];
#pragma unroll
        for (int c = 0; c < NCH; ++c) val += part[((size_t)c * TB + b) * HD + e];
        val = fmaxf(val, 0.f);
        v[i] = val; s += val; sq += val * val;
    }
    __shared__ float shs[4], shq[4];
    for (int o = 32; o; o >>= 1) { s += __shfl_down(s, o); sq += __shfl_down(sq, o); }
    int w = tid >> 6, lane = tid & 63;
    if (!lane) { shs[w] = s; shq[w] = sq; }
    __syncthreads();
    s  = shs[0] + shs[1] + shs[2] + shs[3];
    sq = shq[0] + shq[1] + shq[2] + shq[3];
    float mean = s / (float)HD;
    float var  = sq / (float)HD - mean * mean;
    float rstd = rsqrtf(var + 1e-6f);
    float p0 = 0.f, p1 = 0.f, p2 = 0.f;
#pragma unroll
    for (int i = 0; i < 4; ++i) {
        int e = i * 256 + tid;
        float f = (v[i] - mean) * rstd * g[e] + be[e];
        p0 += f * Wt[e];
        p1 += f * Wt[HD + e];
        p2 += f * Wt[2 * HD + e];
    }
    for (int o = 32; o; o >>= 1) {
        p0 += __shfl_down(p0, o);
        p1 += __shfl_down(p1, o);
        p2 += __shfl_down(p2, o);
    }
    __shared__ float sh[4][3];
    if (!lane) { sh[w][0] = p0; sh[w][1] = p1; sh[w][2] = p2; }
    __syncthreads();
    if (tid < 3)
        out[b * 3 + tid] = sh[0][tid] + sh[1][tid] + sh[2][tid] + sh[3][tid] + ob[tid];
}

// ---------------------------------------------------------------------------
extern "C" void kernel_launch(void* const* d_in, const int* in_sizes, int n_in,
                              void* d_out, int out_size, void* d_ws, size_t ws_size,
                              hipStream_t stream)
{
    const int*   tok_h  = (const int*)  d_in[0];
    const int*   tok_p  = (const int*)  d_in[1];
    const float* embed  = (const float*)d_in[2];
    const float* W_ih   = (const float*)d_in[3];
    const float* W_hh   = (const float*)d_in[4];
    const float* b_ih   = (const float*)d_in[5];
    const float* b_hh   = (const float*)d_in[6];
    const float* mlp1_W = (const float*)d_in[7];
    const float* mlp1_b = (const float*)d_in[8];
    const float* mlp2_W = (const float*)d_in[9];
    const float* mlp2_b = (const float*)d_in[10];
    const float* out_W  = (const float*)d_in[11];
    const float* out_b  = (const float*)d_in[12];
    const float* ln0_g  = (const float*)d_in[13];
    const float* ln0_b  = (const float*)d_in[14];
    const float* ln1_g  = (const float*)d_in[15];
    const float* ln1_b  = (const float*)d_in[16];
    const float* ln2_g  = (const float*)d_in[17];
    const float* ln2_b  = (const float*)d_in[18];

    char* ws = (char*)d_ws;
    size_t off = 0;
    bf16*  f_ln0 = (bf16*)(ws + off);  off += (size_t)TB * F4 * 2;            // 1 MB
    float* part  = (float*)(ws + off); off += (size_t)8 * TB * HD * 4;        // 4 MB
    bf16*  f_ln1 = (bf16*)(ws + off);  off += (size_t)TB * HD * 2;
    float* h_fin = (float*)(ws + off); off += (size_t)NROWS * HH * 4;         // 1 MB
    bf16*  h_hi  = (bf16*)(ws + off);  off += (size_t)2 * NROWS * HH * 2;     // 1 MB
    bf16*  h_lo  = (bf16*)(ws + off);  off += (size_t)2 * NROWS * HH * 2;     // 1 MB
    int*   slots = (int*)(ws + off);   off += 4096;   // flags[256] + xinfo[256]
    float* c_buf = (float*)(ws + off); off += (size_t)NROWS * HH * 4;         // 1 MB
    bf16*  W_ihb = (bf16*)(ws + off);  off += (size_t)G4 * EMB * 2;           // 2 MB
    bf16*  W_hhb = (bf16*)(ws + off);  off += (size_t)G4 * HH * 2;            // 2 MB
    // h_f32 (primary): 2 parities x 512 x 512 f32 = 2 MB, aliases h_hi+h_lo
    float* h_f32 = (float*)h_hi;
    int*   xinfo = slots + 256;
    // big region: UNION of xg (primary, 128 MB) and x_bf (fallback-1, 32 MB)
    bf16*  xg   = (bf16*)(ws + off);
    bf16*  x_bf = (bf16*)(ws + off);
    const size_t need_primary = off + (size_t)2 * TT * TB * G4 * 2;   // +128 MB
    const size_t need_f1      = off + (size_t)2 * TT * TB * EMB * 2;  // +32 MB

    // zero h region + slots/xinfo (contiguous)
    (void)hipMemsetAsync(h_hi, 0, (size_t)4 * NROWS * HH * 2 + 4096, stream);

    const size_t HS = (size_t)NROWS * HH;
    if (ws_size >= need_primary) {
        k_cvt<<<512, 256, 0, stream>>>(W_ih, W_ihb, G4 * EMB / 4);
        k_xproj2<<<dim3(512, 8), 256, 0, stream>>>(tok_h, tok_p, embed, W_ihb,
                                                   b_ih, b_hh, xg);
        void* args[] = {(void*)&xg, (void*)&W_hh, (void*)&b_ih, (void*)&b_hh,
                        (void*)&h_f32, (void*)&h_fin, (void*)&slots, (void*)&xinfo};
        (void)hipLaunchCooperativeKernel((void*)k_persist8, dim3(256), dim3(512),
                                         args, 0, stream);
    } else if (ws_size >= need_f1) {
        k_gather<<<4096, 256, 0, stream>>>(tok_h, tok_p, embed, x_bf);
        void* args[] = {(void*)&x_bf, (void*)&W_ih, (void*)&W_hh,
                        (void*)&b_ih, (void*)&b_hh,
                        (void*)&h_hi, (void*)&h_lo, (void*)&h_fin, (void*)&slots};
        (void)hipLaunchCooperativeKernel((void*)k_persist, dim3(256), dim3(256),
                                         args, 0, stream);
    } else {
        (void)hipMemsetAsync(c_buf, 0, (size_t)NROWS * HH * 4, stream);
        k_cvt<<<512, 256, 0, stream>>>(W_ih, W_ihb, G4 * EMB / 4);
        k_cvt<<<512, 256, 0, stream>>>(W_hh, W_hhb, G4 * HH / 4);
        for (int t = 0; t < TT; ++t) {
            int p = t & 1;
            k_step<0><<<256, 256, 0, stream>>>(x_bf, embed, tok_h, tok_p,
                W_ihb, W_hhb, b_ih, b_hh,
                h_hi + (size_t)p * HS, h_lo + (size_t)p * HS,
                h_hi + (size_t)(p ^ 1) * HS, h_lo + (size_t)(p ^ 1) * HS,
                c_buf, h_fin, t);
        }
    }

    // head (fused)
    k_feat_ln0<<<TB, 256, 0, stream>>>(h_fin, ln0_g, ln0_b, f_ln0);
    k_mlp_sk<F4, 8><<<dim3(16, 2, 8), 256, 0, stream>>>(f_ln0, mlp1_W, part);
    k_redln<8><<<TB, 256, 0, stream>>>(part, mlp1_b, ln1_g, ln1_b, f_ln1);
    k_mlp_sk<HD, 4><<<dim3(16, 2, 4), 256, 0, stream>>>(f_ln1, mlp2_W, part);
    k_redln_out<4><<<TB, 256, 0, stream>>>(part, mlp2_b, ln2_g, ln2_b,
                                           out_W, out_b, (float*)d_out);
}

// Round 13
// 659.663 us; speedup vs baseline: 1.6361x; 1.0653x over previous
//
#include <hip/hip_runtime.h>
#include <hip/hip_bf16.h>

typedef __hip_bfloat16 bf16;
typedef __attribute__((ext_vector_type(8))) short short8;
typedef __attribute__((ext_vector_type(4))) short s16x4;
typedef __attribute__((ext_vector_type(4))) float f32x4;
typedef __attribute__((ext_vector_type(2))) float f32x2;

#define TB 128      // batch
#define TT 128      // time
#define EMB 512     // embed dim
#define HH 512      // per-direction hidden
#define G4 2048     // 4*HH gate dim
#define NROWS 512   // 4 runs * 128 batch
#define F4 4096     // feature dim
#define HD 1024     // mlp hidden
#define SLABW 32768 // 16B words per (s,t) slab in fragment layout (8*8*8*64)

__device__ __forceinline__ bf16 f2bf(float x){ return __float2bfloat16(x); }
__device__ __forceinline__ float bf2f(bf16 x){ return __bfloat162float(x); }

// fast gates: v_exp_f32 + v_rcp_f32; saturate cleanly (rcp(inf)=0), no NaN
__device__ __forceinline__ float fsigm(float x){
    return __builtin_amdgcn_rcpf(1.f + __builtin_amdgcn_exp2f(-1.44269504089f * x));
}
__device__ __forceinline__ float ftanh(float x){
    float t = __builtin_amdgcn_exp2f(2.88539008178f * x);
    return 1.f - 2.f * __builtin_amdgcn_rcpf(t + 1.f);
}

__device__ __forceinline__ short8 pack8(float4 a, float4 b){
    short8 r;
    r[0] = (short)__bfloat16_as_ushort(f2bf(a.x));
    r[1] = (short)__bfloat16_as_ushort(f2bf(a.y));
    r[2] = (short)__bfloat16_as_ushort(f2bf(a.z));
    r[3] = (short)__bfloat16_as_ushort(f2bf(a.w));
    r[4] = (short)__bfloat16_as_ushort(f2bf(b.x));
    r[5] = (short)__bfloat16_as_ushort(f2bf(b.y));
    r[6] = (short)__bfloat16_as_ushort(f2bf(b.z));
    r[7] = (short)__bfloat16_as_ushort(f2bf(b.w));
    return r;
}

// ---------------------------------------------------------------------------
// f32 -> bf16 conversion
// ---------------------------------------------------------------------------
__global__ __launch_bounds__(256) void k_cvt(const float* __restrict__ src,
                                             bf16* __restrict__ dst, int n4)
{
    for (int i = blockIdx.x * 256 + threadIdx.x; i < n4; i += gridDim.x * 256) {
        float4 v = reinterpret_cast<const float4*>(src)[i];
        s16x4 o;
        o[0] = (short)__bfloat16_as_ushort(f2bf(v.x));
        o[1] = (short)__bfloat16_as_ushort(f2bf(v.y));
        o[2] = (short)__bfloat16_as_ushort(f2bf(v.z));
        o[3] = (short)__bfloat16_as_ushort(f2bf(v.w));
        reinterpret_cast<s16x4*>(dst)[i] = o;
    }
}

// ---------------------------------------------------------------------------
// Gather embed rows to bf16 x_bf[s][t][b][e]  (fallback-1 path only)
// ---------------------------------------------------------------------------
__global__ __launch_bounds__(256) void k_gather(
    const int* __restrict__ tok_h, const int* __restrict__ tok_p,
    const float* __restrict__ embed, bf16* __restrict__ x_bf)
{
    const int total4 = 2 * TT * TB * (EMB / 4);
    for (int g = blockIdx.x * 256 + threadIdx.x; g < total4; g += gridDim.x * 256) {
        int e4 = g & (EMB / 4 - 1);
        int b  = (g >> 7) & 127;
        int t  = (g >> 14) & 127;
        int s  = g >> 21;
        int tok = (s ? tok_p : tok_h)[b * TT + t];
        float4 v = reinterpret_cast<const float4*>(embed + (size_t)tok * EMB)[e4];
        s16x4 o;
        o[0] = (short)__bfloat16_as_ushort(f2bf(v.x));
        o[1] = (short)__bfloat16_as_ushort(f2bf(v.y));
        o[2] = (short)__bfloat16_as_ushort(f2bf(v.z));
        o[3] = (short)__bfloat16_as_ushort(f2bf(v.w));
        reinterpret_cast<s16x4*>(x_bf + (((size_t)s * TT + t) * TB + b) * EMB)[e4] = o;
    }
}

// ---------------------------------------------------------------------------
// xproj3: xg in CONSUMER-FRAGMENT layout.
// 16B word index within slab: ((B1*8 + cb)*8 + wc)*64 + (kq*16+l16)
//   slab = (s*TT+t) * SLABW  (SLABW = 32768 words; round-12 bug was 4096)
//   B1 = b>>4, cb = 64-col block within gate, wc = gate*2 + mhalf
//   word content: 8 bf16 [nt*4+q] = value(b = B1*16+kq*4+q,
//                       col = gate*512 + cb*64 + (2*mhalf+nt)*16 + l16)
// Producer epilogue: 8 x 16B fully-coalesced stores per thread (1KB/wave).
// grid (512, 8): mb fastest (same-A blocks co-XCD).
// ---------------------------------------------------------------------------
__global__ __launch_bounds__(256) void k_xproj3(
    const int* __restrict__ tok_h, const int* __restrict__ tok_p,
    const float* __restrict__ embed, const bf16* __restrict__ W_ihb,
    const float* __restrict__ b_ih, const float* __restrict__ b_hh,
    bf16* __restrict__ xg)
{
    __shared__ __align__(16) short As[64][512];
    const int mb = blockIdx.x;      // 0..511 (64-row slabs)  [fastest dim]
    const int nb = blockIdx.y;      // 0..7 (256-col slabs)
    const int tid = threadIdx.x;
    const int w = tid >> 6, lane = tid & 63, l16 = lane & 15, kq = lane >> 4;
    const int m0 = mb * 64;
    const int s  = m0 >> 14;
    const int tt = (m0 >> 7) & 127;
    const int bbase = m0 & 127;     // 0 or 64
    const int* tp = s ? tok_p : tok_h;

#pragma unroll
    for (int it = 0; it < 16; ++it) {
        int idx = it * 256 + tid;
        int row = idx >> 6;
        int ch  = idx & 63;
        int tok = tp[(bbase + row) * TT + tt];
        const float* er = embed + (size_t)tok * EMB + ch * 8;
        float4 v0 = *(const float4*)er;
        float4 v1 = *(const float4*)(er + 4);
        *(short8*)&As[row][(ch ^ (row & 7)) * 8] = pack8(v0, v1);
    }
    __syncthreads();

    const int c0 = nb * 256 + w * 64;
    f32x4 acc[4][4];
#pragma unroll
    for (int mt = 0; mt < 4; ++mt)
#pragma unroll
        for (int nt = 0; nt < 4; ++nt) acc[mt][nt] = (f32x4)0.f;

    for (int kk = 0; kk < 16; ++kk) {
        short8 bfr[4];
#pragma unroll
        for (int nt = 0; nt < 4; ++nt)
            bfr[nt] = *(const short8*)(W_ihb + (size_t)(c0 + nt * 16 + l16) * EMB + kk * 32 + kq * 8);
#pragma unroll
        for (int mt = 0; mt < 4; ++mt) {
            int row = mt * 16 + l16;
            short8 a = *(const short8*)&As[row][(((kk * 4 + kq) ^ (row & 7)) * 8)];
#pragma unroll
            for (int nt = 0; nt < 4; ++nt)
                acc[mt][nt] = __builtin_amdgcn_mfma_f32_16x16x32_bf16(a, bfr[nt], acc[mt][nt], 0, 0, 0);
        }
    }

    // epilogue: fragment-order coalesced stores
    const int gate = nb >> 1;
    const int cbp  = (nb & 1) * 4 + w;
    const size_t slab = ((size_t)s * TT + tt) * SLABW;   // 16B words per slab
    const int lanew = kq * 16 + l16;
#pragma unroll
    for (int mt = 0; mt < 4; ++mt) {
        int B1 = (bbase >> 4) + mt;
#pragma unroll
        for (int mh = 0; mh < 2; ++mh) {
            int wc = gate * 2 + mh;
            size_t word = slab + (((size_t)(B1 * 8 + cbp) * 8 + wc) * 64 + lanew);
            short8 o;
#pragma unroll
            for (int nt = 0; nt < 2; ++nt) {
                int nt4 = mh * 2 + nt;
                int colx = nb * 256 + w * 64 + nt4 * 16 + l16;
                float bias = b_ih[colx] + b_hh[colx];
#pragma unroll
                for (int q = 0; q < 4; ++q)
                    o[nt * 4 + q] = (short)__bfloat16_as_ushort(f2bf(acc[mt][nt4][q] + bias));
            }
            *(short8*)(xg + word * 8) = o;
        }
    }
}

// ---------------------------------------------------------------------------
// PERSISTENT LSTM v10 (cooperative) = round-11 v8 (proven 499 us) +
// xg fragment layout (1 dwordx4 prefetch/step, vmcnt(1)); slab stride FIXED
// to SLABW=32768. Flags: proven agent-atomic barrier (round-11), slots
// padded 128B/rgroup. h data: local-XCD L2 (sc0) when co-located, MALL else.
// ---------------------------------------------------------------------------
__global__ __launch_bounds__(512, 1) void k_persist10(
    const bf16* __restrict__ xg, const float* __restrict__ W_hh,
    const float* __restrict__ b_ih, const float* __restrict__ b_hh,
    float* __restrict__ h_f32, float* __restrict__ h_fin,
    int* __restrict__ slots, int* __restrict__ xinfo)
{
    __shared__ __align__(16) short hstage[2][16][512];   // 32 KB (hi,lo)
    __shared__ float ga[16][16][18];                     // 18 KB

    const int tid = threadIdx.x;
    const int bid = blockIdx.x;
    const int rg = bid & 31;          // rgroup (16 rows); bid%8 == rg%8
    const int cb = bid >> 5;          // 0..7 col-block (64 h-cols)
    const int w = tid >> 6, lane = tid & 63, l16 = lane & 15, kq = lane >> 4;
    const int j0 = cb * 64;
    const int r0 = rg * 16;
    const int run = rg >> 3;          // 0 hypF, 1 hypB, 2 premF, 3 premB
    const int s = run >> 1, dirb = run & 1;

    // ---- co-location detection (safe under cooperative residency) ----
    bool mall = false;
    {
        int myx;
        asm volatile("s_getreg_b32 %0, hwreg(HW_REG_XCC_ID)" : "=s"(myx));
        if (tid == 0)
            __hip_atomic_store(&xinfo[bid], (myx & 15) + 1,
                               __ATOMIC_RELAXED, __HIP_MEMORY_SCOPE_AGENT);
        int v0 = 0;
        for (int c = 0; c < 8; ++c) {
            int v;
            do {
                v = __hip_atomic_load(&xinfo[c * 32 + rg],
                                      __ATOMIC_RELAXED, __HIP_MEMORY_SCOPE_AGENT);
                if (!v) __builtin_amdgcn_s_sleep(2);
            } while (!v);
            if (c == 0) v0 = v;
            else if (v != v0) mall = true;
        }
    }

    // ---- W_hh register frags: wave w owns ntiles 2w, 2w+1 ----
    short8 Bf[2][16];
#pragma unroll
    for (int nt = 0; nt < 2; ++nt) {
        int n = 2 * w + nt;
        int gcol = (n >> 2) * HH + j0 + (n & 3) * 16 + l16;
        const float* wr = W_hh + (size_t)gcol * HH;
#pragma unroll
        for (int kk = 0; kk < 16; ++kk) {
            float4 v0 = *(const float4*)(wr + kk * 32 + kq * 8);
            float4 v1 = *(const float4*)(wr + kk * 32 + kq * 8 + 4);
            Bf[nt][kk] = pack8(v0, v1);
        }
    }

    const int urow = tid >> 5;        // 0..15
    const int jseg = tid & 31;        // 16-f32 segment / 2-cell col pair
    float bsum[2][4];
#pragma unroll
    for (int e = 0; e < 2; ++e)
#pragma unroll
        for (int g = 0; g < 4; ++g) {
            int j = g * HH + j0 + jseg * 2 + e;
            bsum[e][g] = b_ih[j] + b_hh[j];
        }
    float creg[2] = {0.f, 0.f};
    const size_t HSF = (size_t)NROWS * HH;

    // fragment-layout word offset (16B words) within a (s,t) slab
    const size_t woff = (((size_t)(rg & 7) * 8 + cb) * 8 + w) * 64 + lane;

    // prologue: xg prefetch for t=0
    short8 xp;
    {
        int te0 = dirb ? (TT - 1) : 0;
        xp = *(const short8*)((const char*)xg +
                              (((size_t)(s * TT + te0)) * SLABW + woff) * 16);
    }

    for (int t = 0; t < TT; ++t) {
        const int p = t & 1;

        // ---- h loads: local-XCD L2 (sc0) if co-located, else MALL ----
        f32x4 hv[4];
        {
            unsigned long long a = (unsigned long long)(
                h_f32 + (size_t)p * HSF + (size_t)(r0 + urow) * HH + jseg * 16);
            if (mall) {
#pragma unroll
                for (int i = 0; i < 4; ++i)
                    asm volatile("global_load_dwordx4 %0, %1, off sc0 sc1"
                                 : "=v"(hv[i]) : "v"(a + i * 16));
            } else {
#pragma unroll
                for (int i = 0; i < 4; ++i)
                    asm volatile("global_load_dwordx4 %0, %1, off sc0"
                                 : "=v"(hv[i]) : "v"(a + i * 16));
            }
        }
        asm volatile("s_waitcnt vmcnt(0)" ::: "memory");
        __builtin_amdgcn_sched_barrier(0);

        // ---- stage hi/lo to LDS (XOR-swizzled) ----
#pragma unroll
        for (int half = 0; half < 2; ++half) {
            short8 hi, lo;
#pragma unroll
            for (int i2 = 0; i2 < 8; ++i2) {
                float v = hv[half * 2 + (i2 >> 2)][i2 & 3];
                bf16 hb = f2bf(v);
                hi[i2] = (short)__bfloat16_as_ushort(hb);
                lo[i2] = (short)__bfloat16_as_ushort(f2bf(v - bf2f(hb)));
            }
            int ch = (2 * jseg + half) ^ (urow & 7);
            *(short8*)&hstage[0][urow][ch * 8] = hi;
            *(short8*)&hstage[1][urow][ch * 8] = lo;
        }

        // acc init from prefetched xg word (bf16 -> f32 is a shift)
        f32x4 acc[2];
#pragma unroll
        for (int nt = 0; nt < 2; ++nt)
#pragma unroll
            for (int q = 0; q < 4; ++q)
                acc[nt][q] = __uint_as_float(
                    ((unsigned)(unsigned short)xp[nt * 4 + q]) << 16);

        __syncthreads();   // sync #1: hstage ready

        // ---- MFMA: gates += (h_lo + h_hi) @ W_hh^T ----
#pragma unroll
        for (int kk = 0; kk < 16; ++kk) {
            int ch = ((kk * 4 + kq) ^ (l16 & 7)) * 8;
            short8 ahi = *(const short8*)&hstage[0][l16][ch];
            short8 alo = *(const short8*)&hstage[1][l16][ch];
#pragma unroll
            for (int nt = 0; nt < 2; ++nt) {
                acc[nt] = __builtin_amdgcn_mfma_f32_16x16x32_bf16(alo, Bf[nt][kk], acc[nt], 0, 0, 0);
                acc[nt] = __builtin_amdgcn_mfma_f32_16x16x32_bf16(ahi, Bf[nt][kk], acc[nt], 0, 0, 0);
            }
        }

        // ---- gate exchange ----
#pragma unroll
        for (int nt = 0; nt < 2; ++nt)
#pragma unroll
            for (int q = 0; q < 4; ++q)
                ga[2 * w + nt][kq * 4 + q][l16] = acc[nt][q];
        __syncthreads();   // sync #2: ga ready

        // ---- cell update (fast gates) ----
        float hn2[2];
#pragma unroll
        for (int e = 0; e < 2; ++e) {
            int jc = jseg * 2 + e;
            int sub = jc >> 4, c15 = jc & 15;
            float pi = ga[0 + sub][urow][c15]  + bsum[e][0];
            float pf = ga[4 + sub][urow][c15]  + bsum[e][1];
            float pg = ga[8 + sub][urow][c15]  + bsum[e][2];
            float po = ga[12 + sub][urow][c15] + bsum[e][3];
            float cn = fsigm(pf) * creg[e] + fsigm(pi) * ftanh(pg);
            float hn = fsigm(po) * ftanh(cn);
            creg[e] = cn;
            hn2[e] = hn;
        }
        // h store — first vmem op after full drain
        {
            unsigned long long a = (unsigned long long)(
                h_f32 + (size_t)(p ^ 1) * HSF + (size_t)(r0 + urow) * HH + j0 + jseg * 2);
            f32x2 val; val[0] = hn2[0]; val[1] = hn2[1];
            if (mall)
                asm volatile("global_store_dwordx2 %0, %1, off sc0 sc1"
                             :: "v"(a), "v"(val) : "memory");
            else
                asm volatile("global_store_dwordx2 %0, %1, off sc0"
                             :: "v"(a), "v"(val) : "memory");
        }
        if (t == TT - 1) {
            size_t fb = (size_t)(r0 + urow) * HH + j0 + jseg * 2;
            h_fin[fb] = hn2[0];
            h_fin[fb + 1] = hn2[1];
            break;
        }

        // ---- xg prefetch for t+1 (1 dwordx4, after store) ----
        {
            int ten = dirb ? (TT - 2 - t) : (t + 1);
            unsigned long long xa = (unsigned long long)xg +
                (((size_t)(s * TT + ten)) * SLABW + woff) * 16;
            asm volatile("global_load_dwordx4 %0, %1, off"
                         : "=v"(xp) : "v"(xa));
        }
        asm volatile("s_waitcnt vmcnt(1)" ::: "memory");  // h store drained
        __syncthreads();   // sync #3: all waves' stores drained
        if (tid == 0)
            __hip_atomic_store(&slots[rg * 32 + cb], t + 1,
                               __ATOMIC_RELAXED, __HIP_MEMORY_SCOPE_AGENT);
        // ---- all-wave poll via AGENT atomics (proven round-11 path) ----
        {
            int sidx = rg * 32 + (lane & 7);
            while (true) {
                int v = (lane < 8)
                    ? __hip_atomic_load(&slots[sidx],
                                        __ATOMIC_RELAXED, __HIP_MEMORY_SCOPE_AGENT)
                    : 0x7fffffff;
                if (__all(v >= t + 1)) break;
                __builtin_amdgcn_s_sleep(1);
            }
        }
    }
}

// ---------------------------------------------------------------------------
// FALLBACK-1: cooperative persistent kernel (round-4 proven)
// ---------------------------------------------------------------------------
__global__ __launch_bounds__(256) void k_persist(
    const bf16* __restrict__ x_bf,
    const float* __restrict__ W_ih, const float* __restrict__ W_hh,
    const float* __restrict__ b_ih, const float* __restrict__ b_hh,
    bf16* __restrict__ h_hi, bf16* __restrict__ h_lo,
    float* __restrict__ h_fin, int* slots)
{
    __shared__ short Wl[4 * 16 * 16 * 64];
    __shared__ float ga[4][64][17];

    const int tid = threadIdx.x;
    const int bx  = blockIdx.x;
    const int mi  = bx & 7;
    const int cj  = bx >> 3;
    const int w    = tid >> 6;
    const int lane = tid & 63;
    const int l16 = lane & 15;
    const int kq  = lane >> 4;
    const int j0  = cj * 16;
    const int r0  = mi * 64;
    const int run = mi >> 1;
    const int s   = run >> 1;
    const int dirb = run & 1;

    {
        int gc  = tid >> 2;
        int g   = gc >> 4, c = gc & 15;
        int kq4 = tid & 3;
        const float* wxr = W_ih + (size_t)(g * HH + j0 + c) * EMB;
        const float* whr = W_hh + (size_t)(g * HH + j0 + c) * HH;
        for (int kb = 0; kb < 16; ++kb) {
            int k  = kq4 * 128 + kb * 8;
            int kk = k >> 5;
            int eq = (k >> 3) & 3;
            float4 x0 = *(const float4*)(wxr + k);
            float4 x1 = *(const float4*)(wxr + k + 4);
            float4 h0 = *(const float4*)(whr + k);
            float4 h1 = *(const float4*)(whr + k + 4);
            int base = ((g * 16 + kk) * 16 + c) * 64;
            int sx = eq ^ (c & 7);
            int sh = (eq + 4) ^ (c & 7);
            *(short8*)&Wl[base + sx * 8] = pack8(x0, x1);
            *(short8*)&Wl[base + sh * 8] = pack8(h0, h1);
        }
    }

    float bsum[4];
    {
        int j = j0 + (tid & 15);
#pragma unroll
        for (int g = 0; g < 4; ++g) bsum[g] = b_ih[g * HH + j] + b_hh[g * HH + j];
    }
    float creg[4] = {0.f, 0.f, 0.f, 0.f};
    __syncthreads();

    const size_t HS = (size_t)NROWS * HH;
    for (int t = 0; t < TT; ++t) {
        const int p  = t & 1;
        const int te = dirb ? (TT - 1 - t) : t;
        const bf16* hb = h_hi + (size_t)p * HS;
        const bf16* lb = h_lo + (size_t)p * HS;
        const bf16* xr0 = x_bf + ((size_t)(s * TT + te) * TB) * EMB;

        f32x4 acc[4];
#pragma unroll
        for (int mt = 0; mt < 4; ++mt) acc[mt] = (f32x4)0.f;

        const bf16 *ph[4], *pl[4], *px[4];
#pragma unroll
        for (int mt = 0; mt < 4; ++mt) {
            int r = r0 + mt * 16 + l16;
            ph[mt] = hb + (size_t)r * HH;
            pl[mt] = lb + (size_t)r * HH;
            px[mt] = xr0 + (size_t)(r & 127) * EMB;
        }

        for (int kk = 0; kk < 16; ++kk) {
            int cbse = ((w * 16 + kk) * 16 + l16) * 64;
            short8 fx = *(const short8*)&Wl[cbse + ((kq ^ (lane & 7)) * 8)];
            short8 fh = *(const short8*)&Wl[cbse + (((kq + 4) ^ (lane & 7)) * 8)];
            int k0 = kk * 32 + kq * 8;
#pragma unroll
            for (int mt = 0; mt < 4; ++mt) {
                short8 ax  = *(const short8*)(px[mt] + k0);
                short8 ahi = *(const short8*)(ph[mt] + k0);
                short8 alo = *(const short8*)(pl[mt] + k0);
                acc[mt] = __builtin_amdgcn_mfma_f32_16x16x32_bf16(ax,  fx, acc[mt], 0, 0, 0);
                acc[mt] = __builtin_amdgcn_mfma_f32_16x16x32_bf16(alo, fh, acc[mt], 0, 0, 0);
                acc[mt] = __builtin_amdgcn_mfma_f32_16x16x32_bf16(ahi, fh, acc[mt], 0, 0, 0);
            }
        }
#pragma unroll
        for (int mt = 0; mt < 4; ++mt)
#pragma unroll
            for (int q = 0; q < 4; ++q)
                ga[w][mt * 16 + kq * 4 + q][l16] = acc[mt][q];
        __syncthreads();

        bf16* hob = h_hi + (size_t)(p ^ 1) * HS;
        bf16* lob = h_lo + (size_t)(p ^ 1) * HS;
        const int colc = tid & 15;
        const int j = j0 + colc;
#pragma unroll
        for (int q = 0; q < 4; ++q) {
            int rl = (tid >> 4) + q * 16;
            int r  = r0 + rl;
            float pi = ga[0][rl][colc] + bsum[0];
            float pf = ga[1][rl][colc] + bsum[1];
            float pg = ga[2][rl][colc] + bsum[2];
            float po = ga[3][rl][colc] + bsum[3];
            float si = 1.f / (1.f + expf(-pi));
            float sf = 1.f / (1.f + expf(-pf));
            float so = 1.f / (1.f + expf(-po));
            float tg = tanhf(pg);
            float cn = sf * creg[q] + si * tg;
            float hn = so * tanhf(cn);
            creg[q] = cn;
            size_t idx = (size_t)r * HH + j;
            bf16 hi = f2bf(hn);
            hob[idx] = hi;
            lob[idx] = f2bf(hn - bf2f(hi));
            if (t == TT - 1) h_fin[idx] = hn;
        }
        if (t == TT - 1) break;

        __syncthreads();
        if (tid == 0)
            __hip_atomic_store(&slots[mi * 32 + cj], t + 1,
                               __ATOMIC_RELEASE, __HIP_MEMORY_SCOPE_AGENT);
        if (tid < 64) {
            const int tgt = t + 1;
            while (true) {
                int v = (lane < 32)
                    ? __hip_atomic_load(&slots[mi * 32 + lane],
                                        __ATOMIC_RELAXED, __HIP_MEMORY_SCOPE_AGENT)
                    : tgt;
                if (__all(v >= tgt)) break;
                __builtin_amdgcn_s_sleep(1);
            }
            __builtin_amdgcn_fence(__ATOMIC_ACQUIRE, "agent");
        }
        __syncthreads();
    }
}

// ---------------------------------------------------------------------------
// FALLBACK-2: per-step kernel (round-3), x gathered from embed
// ---------------------------------------------------------------------------
template<int GATH>
__global__ __launch_bounds__(256) void k_step(
    const bf16* __restrict__ x_bf, const float* __restrict__ embed,
    const int* __restrict__ tok_h, const int* __restrict__ tok_p,
    const bf16* __restrict__ W_ihb, const bf16* __restrict__ W_hhb,
    const float* __restrict__ b_ih, const float* __restrict__ b_hh,
    const bf16* __restrict__ h_hi_in, const bf16* __restrict__ h_lo_in,
    bf16* __restrict__ h_hi_out, bf16* __restrict__ h_lo_out,
    float* __restrict__ c_buf, float* __restrict__ h_fin, int t)
{
    __shared__ float lds[4][64][17];

    const int blk = blockIdx.x;
    const int mi = blk >> 5;
    const int ji = blk & 31;
    const int w    = threadIdx.x >> 6;
    const int lane = threadIdx.x & 63;
    const int l16 = lane & 15;
    const int kq  = lane >> 4;

    const int run = mi >> 1;
    const int s   = run >> 1;
    const int te  = (run & 1) ? (TT - 1 - t) : t;
    const int r0  = mi * 64;

    const bf16*  hhp[4];
    const bf16*  hlp[4];
    const bf16*  xbp[4];
    const float* xfp[4];
#pragma unroll
    for (int mt = 0; mt < 4; ++mt) {
        int r = r0 + mt * 16 + l16;
        hhp[mt] = h_hi_in + (size_t)r * HH;
        hlp[mt] = h_lo_in + (size_t)r * HH;
        int b = r & 127;
        if (GATH) {
            xbp[mt] = x_bf + (((size_t)s * TT + te) * TB + b) * EMB;
        } else {
            int tok = (s ? tok_p : tok_h)[b * TT + te];
            xfp[mt] = embed + (size_t)tok * EMB;
        }
    }

    const int gcol = w * HH + ji * 16 + l16;
    const bf16* wh = W_hhb + (size_t)gcol * HH;
    const bf16* wx = W_ihb + (size_t)gcol * EMB;

    f32x4 acc[4];
#pragma unroll
    for (int mt = 0; mt < 4; ++mt) acc[mt] = (f32x4)0.f;

    for (int kk = 0; kk < HH / 32; ++kk) {
        const int k0 = kk * 32 + kq * 8;
        short8 bwh = *reinterpret_cast<const short8*>(wh + k0);
        short8 bwx = *reinterpret_cast<const short8*>(wx + k0);
#pragma unroll
        for (int mt = 0; mt < 4; ++mt) {
            short8 ax;
            if (GATH) {
                ax = *reinterpret_cast<const short8*>(xbp[mt] + k0);
            } else {
                float4 v0 = *reinterpret_cast<const float4*>(xfp[mt] + k0);
                float4 v1 = *reinterpret_cast<const float4*>(xfp[mt] + k0 + 4);
                ax = pack8(v0, v1);
            }
            short8 ahi = *reinterpret_cast<const short8*>(hhp[mt] + k0);
            short8 alo = *reinterpret_cast<const short8*>(hlp[mt] + k0);
            acc[mt] = __builtin_amdgcn_mfma_f32_16x16x32_bf16(ax,  bwx, acc[mt], 0, 0, 0);
            acc[mt] = __builtin_amdgcn_mfma_f32_16x16x32_bf16(alo, bwh, acc[mt], 0, 0, 0);
            acc[mt] = __builtin_amdgcn_mfma_f32_16x16x32_bf16(ahi, bwh, acc[mt], 0, 0, 0);
        }
    }
#pragma unroll
    for (int mt = 0; mt < 4; ++mt)
#pragma unroll
        for (int q = 0; q < 4; ++q)
            lds[w][mt * 16 + kq * 4 + q][l16] = acc[mt][q];
    __syncthreads();

    const int tid = threadIdx.x;
#pragma unroll
    for (int q = 0; q < 4; ++q) {
        int cell = tid + q * 256;
        int rl  = cell >> 4;
        int col = cell & 15;
        int r = r0 + rl;
        int j = ji * 16 + col;

        float pi = lds[0][rl][col] + b_ih[j]          + b_hh[j];
        float pf = lds[1][rl][col] + b_ih[HH + j]     + b_hh[HH + j];
        float pg = lds[2][rl][col] + b_ih[2 * HH + j] + b_hh[2 * HH + j];
        float po = lds[3][rl][col] + b_ih[3 * HH + j] + b_hh[3 * HH + j];

        float si = 1.f / (1.f + expf(-pi));
        float sf = 1.f / (1.f + expf(-pf));
        float so = 1.f / (1.f + expf(-po));
        float tg = tanhf(pg);

        size_t idx = (size_t)r * HH + j;
        float cn = sf * c_buf[idx] + si * tg;
        float hn = so * tanhf(cn);
        c_buf[idx] = cn;

        bf16 hi = f2bf(hn);
        h_hi_out[idx] = hi;
        h_lo_out[idx] = f2bf(hn - bf2f(hi));
        if (t == TT - 1) h_fin[idx] = hn;
    }
}

// ---------------------------------------------------------------------------
// features [hyp, prem, prem-hyp, hyp*prem] + LayerNorm(4096); block per row
// ---------------------------------------------------------------------------
__global__ __launch_bounds__(256) void k_feat_ln0(
    const float* __restrict__ h_fin, const float* __restrict__ g,
    const float* __restrict__ be, bf16* __restrict__ f_out)
{
    const int b = blockIdx.x;
    const int tid = threadIdx.x;
    float v[16];
    float s = 0.f, sq = 0.f;
#pragma unroll
    for (int i = 0; i < 16; ++i) {
        int e = i * 256 + tid;
        int region = e >> 10;
        int idx = e & 1023;
        int runh = (idx < 512) ? 0 : 1;
        int jj = idx & 511;
        float hy = h_fin[((size_t)(runh * TB + b)) * HH + jj];
        float pr = h_fin[((size_t)((runh + 2) * TB + b)) * HH + jj];
        float val = (region == 0) ? hy : (region == 1) ? pr
                  : (region == 2) ? (pr - hy) : (hy * pr);
        v[i] = val;
        s += val;
        sq += val * val;
    }
    __shared__ float shs[4], shq[4];
    for (int o = 32; o; o >>= 1) { s += __shfl_down(s, o); sq += __shfl_down(sq, o); }
    int w = tid >> 6, lane = tid & 63;
    if (!lane) { shs[w] = s; shq[w] = sq; }
    __syncthreads();
    s  = shs[0] + shs[1] + shs[2] + shs[3];
    sq = shq[0] + shq[1] + shq[2] + shq[3];
    float mean = s / (float)F4;
    float var  = sq / (float)F4 - mean * mean;
    float rstd = rsqrtf(var + 1e-6f);
#pragma unroll
    for (int i = 0; i < 16; ++i) {
        int e = i * 256 + tid;
        float nv = (v[i] - mean) * rstd * g[e] + be[e];
        f_out[(size_t)b * F4 + e] = f2bf(nv);
    }
}

// ---------------------------------------------------------------------------
// split-K MLP partial GEMM
// ---------------------------------------------------------------------------
template<int KTOT, int NCH>
__global__ __launch_bounds__(256) void k_mlp_sk(
    const bf16* __restrict__ A, const float* __restrict__ Bw,
    float* __restrict__ part)
{
    const int KC = KTOT / NCH;
    const int nb = blockIdx.x, mb = blockIdx.y, kc = blockIdx.z;
    const int w    = threadIdx.x >> 6;
    const int lane = threadIdx.x & 63;
    const int wr = w >> 1, wc = w & 1;
    const int l16 = lane & 15;
    const int kq  = lane >> 4;
    const int m0 = mb * 64 + wr * 32;
    const int c0 = nb * 64 + wc * 32;

    f32x4 acc[2][2];
#pragma unroll
    for (int i = 0; i < 2; ++i)
#pragma unroll
        for (int j = 0; j < 2; ++j) acc[i][j] = (f32x4)0.f;

    for (int kk = kc * (KC / 32); kk < (kc + 1) * (KC / 32); ++kk) {
        const int k0 = kk * 32 + kq * 8;
        short8 a[2], bb[2];
#pragma unroll
        for (int i = 0; i < 2; ++i)
            a[i] = *reinterpret_cast<const short8*>(A + (size_t)(m0 + i * 16 + l16) * KTOT + k0);
#pragma unroll
        for (int j = 0; j < 2; ++j) {
            const float* bp = Bw + (size_t)(c0 + j * 16 + l16) * KTOT + k0;
            float4 v0 = *reinterpret_cast<const float4*>(bp);
            float4 v1 = *reinterpret_cast<const float4*>(bp + 4);
            bb[j] = pack8(v0, v1);
        }
#pragma unroll
        for (int i = 0; i < 2; ++i)
#pragma unroll
            for (int j = 0; j < 2; ++j)
                acc[i][j] = __builtin_amdgcn_mfma_f32_16x16x32_bf16(a[i], bb[j], acc[i][j], 0, 0, 0);
    }
#pragma unroll
    for (int i = 0; i < 2; ++i)
#pragma unroll
        for (int j = 0; j < 2; ++j) {
            int gg = c0 + j * 16 + l16;
#pragma unroll
            for (int q = 0; q < 4; ++q) {
                int m = m0 + i * 16 + kq * 4 + q;
                part[((size_t)kc * TB + m) * HD + gg] = acc[i][j][q];
            }
        }
}

// ---------------------------------------------------------------------------
// fused: reduce partials + bias + relu + LayerNorm(1024) -> bf16
// ---------------------------------------------------------------------------
template<int NCH>
__global__ __launch_bounds__(256) void k_redln(
    const float* __restrict__ part, const float* __restrict__ bias,
    const float* __restrict__ g, const float* __restrict__ be,
    bf16* __restrict__ out)
{
    const int b = blockIdx.x;
    const int tid = threadIdx.x;
    float v[4];
    float s = 0.f, sq = 0.f;
#pragma unroll
    for (int i = 0; i < 4; ++i) {
        int e = i * 256 + tid;
        float val = bias[e];
#pragma unroll
        for (int c = 0; c < NCH; ++c) val += part[((size_t)c * TB + b) * HD + e];
        val = fmaxf(val, 0.f);
        v[i] = val; s += val; sq += val * val;
    }
    __shared__ float shs[4], shq[4];
    for (int o = 32; o; o >>= 1) { s += __shfl_down(s, o); sq += __shfl_down(sq, o); }
    int w = tid >> 6, lane = tid & 63;
    if (!lane) { shs[w] = s; shq[w] = sq; }
    __syncthreads();
    s  = shs[0] + shs[1] + shs[2] + shs[3];
    sq = shq[0] + shq[1] + shq[2] + shq[3];
    float mean = s / (float)HD;
    float var  = sq / (float)HD - mean * mean;
    float rstd = rsqrtf(var + 1e-6f);
#pragma unroll
    for (int i = 0; i < 4; ++i) {
        int e = i * 256 + tid;
        out[(size_t)b * HD + e] = f2bf((v[i] - mean) * rstd * g[e] + be[e]);
    }
}

// ---------------------------------------------------------------------------
// fused: reduce + bias + relu + LayerNorm(1024) + out-proj [128,3] (f32 out)
// ---------------------------------------------------------------------------
template<int NCH>
__global__ __launch_bounds__(256) void k_redln_out(
    const float* __restrict__ part, const float* __restrict__ bias,
    const float* __restrict__ g, const float* __restrict__ be,
    const float* __restrict__ Wt, const float* __restrict__ ob,
    float* __restrict__ out)
{
    const int b = blockIdx.x;
    const int tid = threadIdx.x;
    float v[4];
    float s = 0.f, sq = 0.f;
#pragma unroll
    for (int i = 0; i < 4; ++i) {
        int e = i * 256 + tid;
        float val = bias[e];
#pragma unroll
        for (int c = 0; c < NCH; ++c) val += part[((size_t)c * TB + b) * HD + e];
        val = fmaxf(val, 0.f);
        v[i] = val; s += val; sq += val * val;
    }
    __shared__ float shs[4], shq[4];
    for (int o = 32; o; o >>= 1) { s += __shfl_down(s, o); sq += __shfl_down(sq, o); }
    int w = tid >> 6, lane = tid & 63;
    if (!lane) { shs[w] = s; shq[w] = sq; }
    __syncthreads();
    s  = shs[0] + shs[1] + shs[2] + shs[3];
    sq = shq[0] + shq[1] + shq[2] + shq[3];
    float mean = s / (float)HD;
    float var  = sq / (float)HD - mean * mean;
    float rstd = rsqrtf(var + 1e-6f);
    float p0 = 0.f, p1 = 0.f, p2 = 0.f;
#pragma unroll
    for (int i = 0; i < 4; ++i) {
        int e = i * 256 + tid;
        float f = (v[i] - mean) * rstd * g[e] + be[e];
        p0 += f * Wt[e];
        p1 += f * Wt[HD + e];
        p2 += f * Wt[2 * HD + e];
    }
    for (int o = 32; o; o >>= 1) {
        p0 += __shfl_down(p0, o);
        p1 += __shfl_down(p1, o);
        p2 += __shfl_down(p2, o);
    }
    __shared__ float sh[4][3];
    if (!lane) { sh[w][0] = p0; sh[w][1] = p1; sh[w][2] = p2; }
    __syncthreads();
    if (tid < 3)
        out[b * 3 + tid] = sh[0][tid] + sh[1][tid] + sh[2][tid] + sh[3][tid] + ob[tid];
}

// ---------------------------------------------------------------------------
extern "C" void kernel_launch(void* const* d_in, const int* in_sizes, int n_in,
                              void* d_out, int out_size, void* d_ws, size_t ws_size,
                              hipStream_t stream)
{
    const int*   tok_h  = (const int*)  d_in[0];
    const int*   tok_p  = (const int*)  d_in[1];
    const float* embed  = (const float*)d_in[2];
    const float* W_ih   = (const float*)d_in[3];
    const float* W_hh   = (const float*)d_in[4];
    const float* b_ih   = (const float*)d_in[5];
    const float* b_hh   = (const float*)d_in[6];
    const float* mlp1_W = (const float*)d_in[7];
    const float* mlp1_b = (const float*)d_in[8];
    const float* mlp2_W = (const float*)d_in[9];
    const float* mlp2_b = (const float*)d_in[10];
    const float* out_W  = (const float*)d_in[11];
    const float* out_b  = (const float*)d_in[12];
    const float* ln0_g  = (const float*)d_in[13];
    const float* ln0_b  = (const float*)d_in[14];
    const float* ln1_g  = (const float*)d_in[15];
    const float* ln1_b  = (const float*)d_in[16];
    const float* ln2_g  = (const float*)d_in[17];
    const float* ln2_b  = (const float*)d_in[18];

    char* ws = (char*)d_ws;
    size_t off = 0;
    bf16*  f_ln0 = (bf16*)(ws + off);  off += (size_t)TB * F4 * 2;            // 1 MB
    float* part  = (float*)(ws + off); off += (size_t)8 * TB * HD * 4;        // 4 MB
    bf16*  f_ln1 = (bf16*)(ws + off);  off += (size_t)TB * HD * 2;
    float* h_fin = (float*)(ws + off); off += (size_t)NROWS * HH * 4;         // 1 MB
    bf16*  h_hi  = (bf16*)(ws + off);  off += (size_t)2 * NROWS * HH * 2;     // 1 MB
    bf16*  h_lo  = (bf16*)(ws + off);  off += (size_t)2 * NROWS * HH * 2;     // 1 MB
    int*   slots = (int*)(ws + off);   off += 4096;   // 32 rg x 128B padded
    int*   xinfo = (int*)(ws + off);   off += 4096;
    float* c_buf = (float*)(ws + off); off += (size_t)NROWS * HH * 4;         // 1 MB
    bf16*  W_ihb = (bf16*)(ws + off);  off += (size_t)G4 * EMB * 2;           // 2 MB
    bf16*  W_hhb = (bf16*)(ws + off);  off += (size_t)G4 * HH * 2;            // 2 MB
    // h_f32 (primary): 2 parities x 512 x 512 f32 = 2 MB, aliases h_hi+h_lo
    float* h_f32 = (float*)h_hi;
    // big region: UNION of xg (primary, 128 MB) and x_bf (fallback-1, 32 MB)
    bf16*  xg   = (bf16*)(ws + off);
    bf16*  x_bf = (bf16*)(ws + off);
    const size_t need_primary = off + (size_t)2 * TT * TB * G4 * 2;   // +128 MB
    const size_t need_f1      = off + (size_t)2 * TT * TB * EMB * 2;  // +32 MB

    // zero h region + slots + xinfo (contiguous)
    (void)hipMemsetAsync(h_hi, 0, (size_t)4 * NROWS * HH * 2 + 8192, stream);

    const size_t HS = (size_t)NROWS * HH;
    if (ws_size >= need_primary) {
        k_cvt<<<512, 256, 0, stream>>>(W_ih, W_ihb, G4 * EMB / 4);
        k_xproj3<<<dim3(512, 8), 256, 0, stream>>>(tok_h, tok_p, embed, W_ihb,
                                                   b_ih, b_hh, xg);
        void* args[] = {(void*)&xg, (void*)&W_hh, (void*)&b_ih, (void*)&b_hh,
                        (void*)&h_f32, (void*)&h_fin, (void*)&slots, (void*)&xinfo};
        (void)hipLaunchCooperativeKernel((void*)k_persist10, dim3(256), dim3(512),
                                         args, 0, stream);
    } else if (ws_size >= need_f1) {
        k_gather<<<4096, 256, 0, stream>>>(tok_h, tok_p, embed, x_bf);
        void* args[] = {(void*)&x_bf, (void*)&W_ih, (void*)&W_hh,
                        (void*)&b_ih, (void*)&b_hh,
                        (void*)&h_hi, (void*)&h_lo, (void*)&h_fin, (void*)&slots};
        (void)hipLaunchCooperativeKernel((void*)k_persist, dim3(256), dim3(256),
                                         args, 0, stream);
    } else {
        (void)hipMemsetAsync(c_buf, 0, (size_t)NROWS * HH * 4, stream);
        k_cvt<<<512, 256, 0, stream>>>(W_ih, W_ihb, G4 * EMB / 4);
        k_cvt<<<512, 256, 0, stream>>>(W_hh, W_hhb, G4 * HH / 4);
        for (int t = 0; t < TT; ++t) {
            int p = t & 1;
            k_step<0><<<256, 256, 0, stream>>>(x_bf, embed, tok_h, tok_p,
                W_ihb, W_hhb, b_ih, b_hh,
                h_hi + (size_t)p * HS, h_lo + (size_t)p * HS,
                h_hi + (size_t)(p ^ 1) * HS, h_lo + (size_t)(p ^ 1) * HS,
                c_buf, h_fin, t);
        }
    }

    // head (fused)
    k_feat_ln0<<<TB, 256, 0, stream>>>(h_fin, ln0_g, ln0_b, f_ln0);
    k_mlp_sk<F4, 8><<<dim3(16, 2, 8), 256, 0, stream>>>(f_ln0, mlp1_W, part);
    k_redln<8><<<TB, 256, 0, stream>>>(part, mlp1_b, ln1_g, ln1_b, f_ln1);
    k_mlp_sk<HD, 4><<<dim3(16, 2, 4), 256, 0, stream>>>(f_ln1, mlp2_W, part);
    k_redln_out<4><<<TB, 256, 0, stream>>>(part, mlp2_b, ln2_g, ln2_b,
                                           out_W, out_b, (float*)d_out);
}

// Round 14
// 641.751 us; speedup vs baseline: 1.6817x; 1.0279x over previous
//
#include <hip/hip_runtime.h>
#include <hip/hip_bf16.h>

typedef __hip_bfloat16 bf16;
typedef __attribute__((ext_vector_type(8))) short short8;
typedef __attribute__((ext_vector_type(4))) short s16x4;
typedef __attribute__((ext_vector_type(4))) float f32x4;
typedef __attribute__((ext_vector_type(2))) float f32x2;

#define TB 128      // batch
#define TT 128      // time
#define EMB 512     // embed dim
#define HH 512      // per-direction hidden
#define G4 2048     // 4*HH gate dim
#define NROWS 512   // 4 runs * 128 batch
#define F4 4096     // feature dim
#define HD 1024     // mlp hidden
#define SLABW 32768 // 16B words per (s,t) slab in fragment layout (8*8*8*64)
#define HROW 520    // hstage row stride in shorts (1040B -> 4-bank shift/row)

__device__ __forceinline__ bf16 f2bf(float x){ return __float2bfloat16(x); }
__device__ __forceinline__ float bf2f(bf16 x){ return __bfloat162float(x); }

// fast gates: v_exp_f32 + v_rcp_f32; saturate cleanly (rcp(inf)=0), no NaN
__device__ __forceinline__ float fsigm(float x){
    return __builtin_amdgcn_rcpf(1.f + __builtin_amdgcn_exp2f(-1.44269504089f * x));
}
__device__ __forceinline__ float ftanh(float x){
    float t = __builtin_amdgcn_exp2f(2.88539008178f * x);
    return 1.f - 2.f * __builtin_amdgcn_rcpf(t + 1.f);
}

__device__ __forceinline__ short8 pack8(float4 a, float4 b){
    short8 r;
    r[0] = (short)__bfloat16_as_ushort(f2bf(a.x));
    r[1] = (short)__bfloat16_as_ushort(f2bf(a.y));
    r[2] = (short)__bfloat16_as_ushort(f2bf(a.z));
    r[3] = (short)__bfloat16_as_ushort(f2bf(a.w));
    r[4] = (short)__bfloat16_as_ushort(f2bf(b.x));
    r[5] = (short)__bfloat16_as_ushort(f2bf(b.y));
    r[6] = (short)__bfloat16_as_ushort(f2bf(b.z));
    r[7] = (short)__bfloat16_as_ushort(f2bf(b.w));
    return r;
}

// ---------------------------------------------------------------------------
// f32 -> bf16 conversion
// ---------------------------------------------------------------------------
__global__ __launch_bounds__(256) void k_cvt(const float* __restrict__ src,
                                             bf16* __restrict__ dst, int n4)
{
    for (int i = blockIdx.x * 256 + threadIdx.x; i < n4; i += gridDim.x * 256) {
        float4 v = reinterpret_cast<const float4*>(src)[i];
        s16x4 o;
        o[0] = (short)__bfloat16_as_ushort(f2bf(v.x));
        o[1] = (short)__bfloat16_as_ushort(f2bf(v.y));
        o[2] = (short)__bfloat16_as_ushort(f2bf(v.z));
        o[3] = (short)__bfloat16_as_ushort(f2bf(v.w));
        reinterpret_cast<s16x4*>(dst)[i] = o;
    }
}

// ---------------------------------------------------------------------------
// Gather embed rows to bf16 x_bf[s][t][b][e]  (fallback-1 path only)
// ---------------------------------------------------------------------------
__global__ __launch_bounds__(256) void k_gather(
    const int* __restrict__ tok_h, const int* __restrict__ tok_p,
    const float* __restrict__ embed, bf16* __restrict__ x_bf)
{
    const int total4 = 2 * TT * TB * (EMB / 4);
    for (int g = blockIdx.x * 256 + threadIdx.x; g < total4; g += gridDim.x * 256) {
        int e4 = g & (EMB / 4 - 1);
        int b  = (g >> 7) & 127;
        int t  = (g >> 14) & 127;
        int s  = g >> 21;
        int tok = (s ? tok_p : tok_h)[b * TT + t];
        float4 v = reinterpret_cast<const float4*>(embed + (size_t)tok * EMB)[e4];
        s16x4 o;
        o[0] = (short)__bfloat16_as_ushort(f2bf(v.x));
        o[1] = (short)__bfloat16_as_ushort(f2bf(v.y));
        o[2] = (short)__bfloat16_as_ushort(f2bf(v.z));
        o[3] = (short)__bfloat16_as_ushort(f2bf(v.w));
        reinterpret_cast<s16x4*>(x_bf + (((size_t)s * TT + t) * TB + b) * EMB)[e4] = o;
    }
}

// ---------------------------------------------------------------------------
// xproj3: xg in CONSUMER-FRAGMENT layout (slab stride SLABW=32768 words).
// ---------------------------------------------------------------------------
__global__ __launch_bounds__(256) void k_xproj3(
    const int* __restrict__ tok_h, const int* __restrict__ tok_p,
    const float* __restrict__ embed, const bf16* __restrict__ W_ihb,
    const float* __restrict__ b_ih, const float* __restrict__ b_hh,
    bf16* __restrict__ xg)
{
    __shared__ __align__(16) short As[64][512];
    const int mb = blockIdx.x;      // 0..511 (64-row slabs)  [fastest dim]
    const int nb = blockIdx.y;      // 0..7 (256-col slabs)
    const int tid = threadIdx.x;
    const int w = tid >> 6, lane = tid & 63, l16 = lane & 15, kq = lane >> 4;
    const int m0 = mb * 64;
    const int s  = m0 >> 14;
    const int tt = (m0 >> 7) & 127;
    const int bbase = m0 & 127;     // 0 or 64
    const int* tp = s ? tok_p : tok_h;

#pragma unroll
    for (int it = 0; it < 16; ++it) {
        int idx = it * 256 + tid;
        int row = idx >> 6;
        int ch  = idx & 63;
        int tok = tp[(bbase + row) * TT + tt];
        const float* er = embed + (size_t)tok * EMB + ch * 8;
        float4 v0 = *(const float4*)er;
        float4 v1 = *(const float4*)(er + 4);
        *(short8*)&As[row][(ch ^ (row & 7)) * 8] = pack8(v0, v1);
    }
    __syncthreads();

    const int c0 = nb * 256 + w * 64;
    f32x4 acc[4][4];
#pragma unroll
    for (int mt = 0; mt < 4; ++mt)
#pragma unroll
        for (int nt = 0; nt < 4; ++nt) acc[mt][nt] = (f32x4)0.f;

    for (int kk = 0; kk < 16; ++kk) {
        short8 bfr[4];
#pragma unroll
        for (int nt = 0; nt < 4; ++nt)
            bfr[nt] = *(const short8*)(W_ihb + (size_t)(c0 + nt * 16 + l16) * EMB + kk * 32 + kq * 8);
#pragma unroll
        for (int mt = 0; mt < 4; ++mt) {
            int row = mt * 16 + l16;
            short8 a = *(const short8*)&As[row][(((kk * 4 + kq) ^ (row & 7)) * 8)];
#pragma unroll
            for (int nt = 0; nt < 4; ++nt)
                acc[mt][nt] = __builtin_amdgcn_mfma_f32_16x16x32_bf16(a, bfr[nt], acc[mt][nt], 0, 0, 0);
        }
    }

    // epilogue: fragment-order coalesced stores
    const int gate = nb >> 1;
    const int cbp  = (nb & 1) * 4 + w;
    const size_t slab = ((size_t)s * TT + tt) * SLABW;   // 16B words per slab
    const int lanew = kq * 16 + l16;
#pragma unroll
    for (int mt = 0; mt < 4; ++mt) {
        int B1 = (bbase >> 4) + mt;
#pragma unroll
        for (int mh = 0; mh < 2; ++mh) {
            int wc = gate * 2 + mh;
            size_t word = slab + (((size_t)(B1 * 8 + cbp) * 8 + wc) * 64 + lanew);
            short8 o;
#pragma unroll
            for (int nt = 0; nt < 2; ++nt) {
                int nt4 = mh * 2 + nt;
                int colx = nb * 256 + w * 64 + nt4 * 16 + l16;
                float bias = b_ih[colx] + b_hh[colx];
#pragma unroll
                for (int q = 0; q < 4; ++q)
                    o[nt * 4 + q] = (short)__bfloat16_as_ushort(f2bf(acc[mt][nt4][q] + bias));
            }
            *(short8*)(xg + word * 8) = o;
        }
    }
}

// ---------------------------------------------------------------------------
// PERSISTENT LSTM v11 (cooperative) = round-13 v10 (proven 450 us) with
// conflict-free LDS:
//  - hstage rows padded to HROW=520 shorts (1040B -> 4-bank shift per row);
//    XOR swizzle removed (chunk index now plain) -> both staging writes and
//    MFMA reads hit the b128 minimum bank cycles
//  - ga pad 18 -> 19 (cell-update reads 4-way -> 2-way/free)
// Everything else identical (proven agent-atomic barrier, sc0 h exchange).
// ---------------------------------------------------------------------------
__global__ __launch_bounds__(512, 1) void k_persist11(
    const bf16* __restrict__ xg, const float* __restrict__ W_hh,
    const float* __restrict__ b_ih, const float* __restrict__ b_hh,
    float* __restrict__ h_f32, float* __restrict__ h_fin,
    int* __restrict__ slots, int* __restrict__ xinfo)
{
    __shared__ __align__(16) short hstage[2][16][HROW];  // 33.3 KB (hi,lo)
    __shared__ float ga[16][16][19];                     // 19.5 KB

    const int tid = threadIdx.x;
    const int bid = blockIdx.x;
    const int rg = bid & 31;          // rgroup (16 rows); bid%8 == rg%8
    const int cb = bid >> 5;          // 0..7 col-block (64 h-cols)
    const int w = tid >> 6, lane = tid & 63, l16 = lane & 15, kq = lane >> 4;
    const int j0 = cb * 64;
    const int r0 = rg * 16;
    const int run = rg >> 3;          // 0 hypF, 1 hypB, 2 premF, 3 premB
    const int s = run >> 1, dirb = run & 1;

    // ---- co-location detection (safe under cooperative residency) ----
    bool mall = false;
    {
        int myx;
        asm volatile("s_getreg_b32 %0, hwreg(HW_REG_XCC_ID)" : "=s"(myx));
        if (tid == 0)
            __hip_atomic_store(&xinfo[bid], (myx & 15) + 1,
                               __ATOMIC_RELAXED, __HIP_MEMORY_SCOPE_AGENT);
        int v0 = 0;
        for (int c = 0; c < 8; ++c) {
            int v;
            do {
                v = __hip_atomic_load(&xinfo[c * 32 + rg],
                                      __ATOMIC_RELAXED, __HIP_MEMORY_SCOPE_AGENT);
                if (!v) __builtin_amdgcn_s_sleep(2);
            } while (!v);
            if (c == 0) v0 = v;
            else if (v != v0) mall = true;
        }
    }

    // ---- W_hh register frags: wave w owns ntiles 2w, 2w+1 ----
    short8 Bf[2][16];
#pragma unroll
    for (int nt = 0; nt < 2; ++nt) {
        int n = 2 * w + nt;
        int gcol = (n >> 2) * HH + j0 + (n & 3) * 16 + l16;
        const float* wr = W_hh + (size_t)gcol * HH;
#pragma unroll
        for (int kk = 0; kk < 16; ++kk) {
            float4 v0 = *(const float4*)(wr + kk * 32 + kq * 8);
            float4 v1 = *(const float4*)(wr + kk * 32 + kq * 8 + 4);
            Bf[nt][kk] = pack8(v0, v1);
        }
    }

    const int urow = tid >> 5;        // 0..15
    const int jseg = tid & 31;        // 16-f32 segment / 2-cell col pair
    float bsum[2][4];
#pragma unroll
    for (int e = 0; e < 2; ++e)
#pragma unroll
        for (int g = 0; g < 4; ++g) {
            int j = g * HH + j0 + jseg * 2 + e;
            bsum[e][g] = b_ih[j] + b_hh[j];
        }
    float creg[2] = {0.f, 0.f};
    const size_t HSF = (size_t)NROWS * HH;

    // fragment-layout word offset (16B words) within a (s,t) slab
    const size_t woff = (((size_t)(rg & 7) * 8 + cb) * 8 + w) * 64 + lane;

    // prologue: xg prefetch for t=0
    short8 xp;
    {
        int te0 = dirb ? (TT - 1) : 0;
        xp = *(const short8*)((const char*)xg +
                              (((size_t)(s * TT + te0)) * SLABW + woff) * 16);
    }

    for (int t = 0; t < TT; ++t) {
        const int p = t & 1;

        // ---- h loads: local-XCD L2 (sc0) if co-located, else MALL ----
        f32x4 hv[4];
        {
            unsigned long long a = (unsigned long long)(
                h_f32 + (size_t)p * HSF + (size_t)(r0 + urow) * HH + jseg * 16);
            if (mall) {
#pragma unroll
                for (int i = 0; i < 4; ++i)
                    asm volatile("global_load_dwordx4 %0, %1, off sc0 sc1"
                                 : "=v"(hv[i]) : "v"(a + i * 16));
            } else {
#pragma unroll
                for (int i = 0; i < 4; ++i)
                    asm volatile("global_load_dwordx4 %0, %1, off sc0"
                                 : "=v"(hv[i]) : "v"(a + i * 16));
            }
        }
        asm volatile("s_waitcnt vmcnt(0)" ::: "memory");
        __builtin_amdgcn_sched_barrier(0);

        // ---- stage hi/lo to LDS (conflict-free padded rows, no XOR) ----
#pragma unroll
        for (int half = 0; half < 2; ++half) {
            short8 hi, lo;
#pragma unroll
            for (int i2 = 0; i2 < 8; ++i2) {
                float v = hv[half * 2 + (i2 >> 2)][i2 & 3];
                bf16 hb = f2bf(v);
                hi[i2] = (short)__bfloat16_as_ushort(hb);
                lo[i2] = (short)__bfloat16_as_ushort(f2bf(v - bf2f(hb)));
            }
            int ch = 2 * jseg + half;
            *(short8*)&hstage[0][urow][ch * 8] = hi;
            *(short8*)&hstage[1][urow][ch * 8] = lo;
        }

        // acc init from prefetched xg word (bf16 -> f32 is a shift)
        f32x4 acc[2];
#pragma unroll
        for (int nt = 0; nt < 2; ++nt)
#pragma unroll
            for (int q = 0; q < 4; ++q)
                acc[nt][q] = __uint_as_float(
                    ((unsigned)(unsigned short)xp[nt * 4 + q]) << 16);

        __syncthreads();   // sync #1: hstage ready

        // ---- MFMA: gates += (h_lo + h_hi) @ W_hh^T ----
#pragma unroll
        for (int kk = 0; kk < 16; ++kk) {
            int ch = (kk * 4 + kq) * 8;
            short8 ahi = *(const short8*)&hstage[0][l16][ch];
            short8 alo = *(const short8*)&hstage[1][l16][ch];
#pragma unroll
            for (int nt = 0; nt < 2; ++nt) {
                acc[nt] = __builtin_amdgcn_mfma_f32_16x16x32_bf16(alo, Bf[nt][kk], acc[nt], 0, 0, 0);
                acc[nt] = __builtin_amdgcn_mfma_f32_16x16x32_bf16(ahi, Bf[nt][kk], acc[nt], 0, 0, 0);
            }
        }

        // ---- gate exchange ----
#pragma unroll
        for (int nt = 0; nt < 2; ++nt)
#pragma unroll
            for (int q = 0; q < 4; ++q)
                ga[2 * w + nt][kq * 4 + q][l16] = acc[nt][q];
        __syncthreads();   // sync #2: ga ready

        // ---- cell update (fast gates) ----
        float hn2[2];
#pragma unroll
        for (int e = 0; e < 2; ++e) {
            int jc = jseg * 2 + e;
            int sub = jc >> 4, c15 = jc & 15;
            float pi = ga[0 + sub][urow][c15]  + bsum[e][0];
            float pf = ga[4 + sub][urow][c15]  + bsum[e][1];
            float pg = ga[8 + sub][urow][c15]  + bsum[e][2];
            float po = ga[12 + sub][urow][c15] + bsum[e][3];
            float cn = fsigm(pf) * creg[e] + fsigm(pi) * ftanh(pg);
            float hn = fsigm(po) * ftanh(cn);
            creg[e] = cn;
            hn2[e] = hn;
        }
        // h store — first vmem op after full drain
        {
            unsigned long long a = (unsigned long long)(
                h_f32 + (size_t)(p ^ 1) * HSF + (size_t)(r0 + urow) * HH + j0 + jseg * 2);
            f32x2 val; val[0] = hn2[0]; val[1] = hn2[1];
            if (mall)
                asm volatile("global_store_dwordx2 %0, %1, off sc0 sc1"
                             :: "v"(a), "v"(val) : "memory");
            else
                asm volatile("global_store_dwordx2 %0, %1, off sc0"
                             :: "v"(a), "v"(val) : "memory");
        }
        if (t == TT - 1) {
            size_t fb = (size_t)(r0 + urow) * HH + j0 + jseg * 2;
            h_fin[fb] = hn2[0];
            h_fin[fb + 1] = hn2[1];
            break;
        }

        // ---- xg prefetch for t+1 (1 dwordx4, after store) ----
        {
            int ten = dirb ? (TT - 2 - t) : (t + 1);
            unsigned long long xa = (unsigned long long)xg +
                (((size_t)(s * TT + ten)) * SLABW + woff) * 16;
            asm volatile("global_load_dwordx4 %0, %1, off"
                         : "=v"(xp) : "v"(xa));
        }
        asm volatile("s_waitcnt vmcnt(1)" ::: "memory");  // h store drained
        __syncthreads();   // sync #3: all waves' stores drained
        if (tid == 0)
            __hip_atomic_store(&slots[rg * 32 + cb], t + 1,
                               __ATOMIC_RELAXED, __HIP_MEMORY_SCOPE_AGENT);
        // ---- all-wave poll via AGENT atomics (proven round-11 path) ----
        {
            int sidx = rg * 32 + (lane & 7);
            while (true) {
                int v = (lane < 8)
                    ? __hip_atomic_load(&slots[sidx],
                                        __ATOMIC_RELAXED, __HIP_MEMORY_SCOPE_AGENT)
                    : 0x7fffffff;
                if (__all(v >= t + 1)) break;
                __builtin_amdgcn_s_sleep(1);
            }
        }
    }
}

// ---------------------------------------------------------------------------
// FALLBACK-1: cooperative persistent kernel (round-4 proven)
// ---------------------------------------------------------------------------
__global__ __launch_bounds__(256) void k_persist(
    const bf16* __restrict__ x_bf,
    const float* __restrict__ W_ih, const float* __restrict__ W_hh,
    const float* __restrict__ b_ih, const float* __restrict__ b_hh,
    bf16* __restrict__ h_hi, bf16* __restrict__ h_lo,
    float* __restrict__ h_fin, int* slots)
{
    __shared__ short Wl[4 * 16 * 16 * 64];
    __shared__ float ga[4][64][17];

    const int tid = threadIdx.x;
    const int bx  = blockIdx.x;
    const int mi  = bx & 7;
    const int cj  = bx >> 3;
    const int w    = tid >> 6;
    const int lane = tid & 63;
    const int l16 = lane & 15;
    const int kq  = lane >> 4;
    const int j0  = cj * 16;
    const int r0  = mi * 64;
    const int run = mi >> 1;
    const int s   = run >> 1;
    const int dirb = run & 1;

    {
        int gc  = tid >> 2;
        int g   = gc >> 4, c = gc & 15;
        int kq4 = tid & 3;
        const float* wxr = W_ih + (size_t)(g * HH + j0 + c) * EMB;
        const float* whr = W_hh + (size_t)(g * HH + j0 + c) * HH;
        for (int kb = 0; kb < 16; ++kb) {
            int k  = kq4 * 128 + kb * 8;
            int kk = k >> 5;
            int eq = (k >> 3) & 3;
            float4 x0 = *(const float4*)(wxr + k);
            float4 x1 = *(const float4*)(wxr + k + 4);
            float4 h0 = *(const float4*)(whr + k);
            float4 h1 = *(const float4*)(whr + k + 4);
            int base = ((g * 16 + kk) * 16 + c) * 64;
            int sx = eq ^ (c & 7);
            int sh = (eq + 4) ^ (c & 7);
            *(short8*)&Wl[base + sx * 8] = pack8(x0, x1);
            *(short8*)&Wl[base + sh * 8] = pack8(h0, h1);
        }
    }

    float bsum[4];
    {
        int j = j0 + (tid & 15);
#pragma unroll
        for (int g = 0; g < 4; ++g) bsum[g] = b_ih[g * HH + j] + b_hh[g * HH + j];
    }
    float creg[4] = {0.f, 0.f, 0.f, 0.f};
    __syncthreads();

    const size_t HS = (size_t)NROWS * HH;
    for (int t = 0; t < TT; ++t) {
        const int p  = t & 1;
        const int te = dirb ? (TT - 1 - t) : t;
        const bf16* hb = h_hi + (size_t)p * HS;
        const bf16* lb = h_lo + (size_t)p * HS;
        const bf16* xr0 = x_bf + ((size_t)(s * TT + te) * TB) * EMB;

        f32x4 acc[4];
#pragma unroll
        for (int mt = 0; mt < 4; ++mt) acc[mt] = (f32x4)0.f;

        const bf16 *ph[4], *pl[4], *px[4];
#pragma unroll
        for (int mt = 0; mt < 4; ++mt) {
            int r = r0 + mt * 16 + l16;
            ph[mt] = hb + (size_t)r * HH;
            pl[mt] = lb + (size_t)r * HH;
            px[mt] = xr0 + (size_t)(r & 127) * EMB;
        }

        for (int kk = 0; kk < 16; ++kk) {
            int cbse = ((w * 16 + kk) * 16 + l16) * 64;
            short8 fx = *(const short8*)&Wl[cbse + ((kq ^ (lane & 7)) * 8)];
            short8 fh = *(const short8*)&Wl[cbse + (((kq + 4) ^ (lane & 7)) * 8)];
            int k0 = kk * 32 + kq * 8;
#pragma unroll
            for (int mt = 0; mt < 4; ++mt) {
                short8 ax  = *(const short8*)(px[mt] + k0);
                short8 ahi = *(const short8*)(ph[mt] + k0);
                short8 alo = *(const short8*)(pl[mt] + k0);
                acc[mt] = __builtin_amdgcn_mfma_f32_16x16x32_bf16(ax,  fx, acc[mt], 0, 0, 0);
                acc[mt] = __builtin_amdgcn_mfma_f32_16x16x32_bf16(alo, fh, acc[mt], 0, 0, 0);
                acc[mt] = __builtin_amdgcn_mfma_f32_16x16x32_bf16(ahi, fh, acc[mt], 0, 0, 0);
            }
        }
#pragma unroll
        for (int mt = 0; mt < 4; ++mt)
#pragma unroll
            for (int q = 0; q < 4; ++q)
                ga[w][mt * 16 + kq * 4 + q][l16] = acc[mt][q];
        __syncthreads();

        bf16* hob = h_hi + (size_t)(p ^ 1) * HS;
        bf16* lob = h_lo + (size_t)(p ^ 1) * HS;
        const int colc = tid & 15;
        const int j = j0 + colc;
#pragma unroll
        for (int q = 0; q < 4; ++q) {
            int rl = (tid >> 4) + q * 16;
            int r  = r0 + rl;
            float pi = ga[0][rl][colc] + bsum[0];
            float pf = ga[1][rl][colc] + bsum[1];
            float pg = ga[2][rl][colc] + bsum[2];
            float po = ga[3][rl][colc] + bsum[3];
            float si = 1.f / (1.f + expf(-pi));
            float sf = 1.f / (1.f + expf(-pf));
            float so = 1.f / (1.f + expf(-po));
            float tg = tanhf(pg);
            float cn = sf * creg[q] + si * tg;
            float hn = so * tanhf(cn);
            creg[q] = cn;
            size_t idx = (size_t)r * HH + j;
            bf16 hi = f2bf(hn);
            hob[idx] = hi;
            lob[idx] = f2bf(hn - bf2f(hi));
            if (t == TT - 1) h_fin[idx] = hn;
        }
        if (t == TT - 1) break;

        __syncthreads();
        if (tid == 0)
            __hip_atomic_store(&slots[mi * 32 + cj], t + 1,
                               __ATOMIC_RELEASE, __HIP_MEMORY_SCOPE_AGENT);
        if (tid < 64) {
            const int tgt = t + 1;
            while (true) {
                int v = (lane < 32)
                    ? __hip_atomic_load(&slots[mi * 32 + lane],
                                        __ATOMIC_RELAXED, __HIP_MEMORY_SCOPE_AGENT)
                    : tgt;
                if (__all(v >= tgt)) break;
                __builtin_amdgcn_s_sleep(1);
            }
            __builtin_amdgcn_fence(__ATOMIC_ACQUIRE, "agent");
        }
        __syncthreads();
    }
}

// ---------------------------------------------------------------------------
// FALLBACK-2: per-step kernel (round-3), x gathered from embed
// ---------------------------------------------------------------------------
template<int GATH>
__global__ __launch_bounds__(256) void k_step(
    const bf16* __restrict__ x_bf, const float* __restrict__ embed,
    const int* __restrict__ tok_h, const int* __restrict__ tok_p,
    const bf16* __restrict__ W_ihb, const bf16* __restrict__ W_hhb,
    const float* __restrict__ b_ih, const float* __restrict__ b_hh,
    const bf16* __restrict__ h_hi_in, const bf16* __restrict__ h_lo_in,
    bf16* __restrict__ h_hi_out, bf16* __restrict__ h_lo_out,
    float* __restrict__ c_buf, float* __restrict__ h_fin, int t)
{
    __shared__ float lds[4][64][17];

    const int blk = blockIdx.x;
    const int mi = blk >> 5;
    const int ji = blk & 31;
    const int w    = threadIdx.x >> 6;
    const int lane = threadIdx.x & 63;
    const int l16 = lane & 15;
    const int kq  = lane >> 4;

    const int run = mi >> 1;
    const int s   = run >> 1;
    const int te  = (run & 1) ? (TT - 1 - t) : t;
    const int r0  = mi * 64;

    const bf16*  hhp[4];
    const bf16*  hlp[4];
    const bf16*  xbp[4];
    const float* xfp[4];
#pragma unroll
    for (int mt = 0; mt < 4; ++mt) {
        int r = r0 + mt * 16 + l16;
        hhp[mt] = h_hi_in + (size_t)r * HH;
        hlp[mt] = h_lo_in + (size_t)r * HH;
        int b = r & 127;
        if (GATH) {
            xbp[mt] = x_bf + (((size_t)s * TT + te) * TB + b) * EMB;
        } else {
            int tok = (s ? tok_p : tok_h)[b * TT + te];
            xfp[mt] = embed + (size_t)tok * EMB;
        }
    }

    const int gcol = w * HH + ji * 16 + l16;
    const bf16* wh = W_hhb + (size_t)gcol * HH;
    const bf16* wx = W_ihb + (size_t)gcol * EMB;

    f32x4 acc[4];
#pragma unroll
    for (int mt = 0; mt < 4; ++mt) acc[mt] = (f32x4)0.f;

    for (int kk = 0; kk < HH / 32; ++kk) {
        const int k0 = kk * 32 + kq * 8;
        short8 bwh = *reinterpret_cast<const short8*>(wh + k0);
        short8 bwx = *reinterpret_cast<const short8*>(wx + k0);
#pragma unroll
        for (int mt = 0; mt < 4; ++mt) {
            short8 ax;
            if (GATH) {
                ax = *reinterpret_cast<const short8*>(xbp[mt] + k0);
            } else {
                float4 v0 = *reinterpret_cast<const float4*>(xfp[mt] + k0);
                float4 v1 = *reinterpret_cast<const float4*>(xfp[mt] + k0 + 4);
                ax = pack8(v0, v1);
            }
            short8 ahi = *reinterpret_cast<const short8*>(hhp[mt] + k0);
            short8 alo = *reinterpret_cast<const short8*>(hlp[mt] + k0);
            acc[mt] = __builtin_amdgcn_mfma_f32_16x16x32_bf16(ax,  bwx, acc[mt], 0, 0, 0);
            acc[mt] = __builtin_amdgcn_mfma_f32_16x16x32_bf16(alo, bwh, acc[mt], 0, 0, 0);
            acc[mt] = __builtin_amdgcn_mfma_f32_16x16x32_bf16(ahi, bwh, acc[mt], 0, 0, 0);
        }
    }
#pragma unroll
    for (int mt = 0; mt < 4; ++mt)
#pragma unroll
        for (int q = 0; q < 4; ++q)
            lds[w][mt * 16 + kq * 4 + q][l16] = acc[mt][q];
    __syncthreads();

    const int tid = threadIdx.x;
#pragma unroll
    for (int q = 0; q < 4; ++q) {
        int cell = tid + q * 256;
        int rl  = cell >> 4;
        int col = cell & 15;
        int r = r0 + rl;
        int j = ji * 16 + col;

        float pi = lds[0][rl][col] + b_ih[j]          + b_hh[j];
        float pf = lds[1][rl][col] + b_ih[HH + j]     + b_hh[HH + j];
        float pg = lds[2][rl][col] + b_ih[2 * HH + j] + b_hh[2 * HH + j];
        float po = lds[3][rl][col] + b_ih[3 * HH + j] + b_hh[3 * HH + j];

        float si = 1.f / (1.f + expf(-pi));
        float sf = 1.f / (1.f + expf(-pf));
        float so = 1.f / (1.f + expf(-po));
        float tg = tanhf(pg);

        size_t idx = (size_t)r * HH + j;
        float cn = sf * c_buf[idx] + si * tg;
        float hn = so * tanhf(cn);
        c_buf[idx] = cn;

        bf16 hi = f2bf(hn);
        h_hi_out[idx] = hi;
        h_lo_out[idx] = f2bf(hn - bf2f(hi));
        if (t == TT - 1) h_fin[idx] = hn;
    }
}

// ---------------------------------------------------------------------------
// features [hyp, prem, prem-hyp, hyp*prem] + LayerNorm(4096); block per row
// ---------------------------------------------------------------------------
__global__ __launch_bounds__(256) void k_feat_ln0(
    const float* __restrict__ h_fin, const float* __restrict__ g,
    const float* __restrict__ be, bf16* __restrict__ f_out)
{
    const int b = blockIdx.x;
    const int tid = threadIdx.x;
    float v[16];
    float s = 0.f, sq = 0.f;
#pragma unroll
    for (int i = 0; i < 16; ++i) {
        int e = i * 256 + tid;
        int region = e >> 10;
        int idx = e & 1023;
        int runh = (idx < 512) ? 0 : 1;
        int jj = idx & 511;
        float hy = h_fin[((size_t)(runh * TB + b)) * HH + jj];
        float pr = h_fin[((size_t)((runh + 2) * TB + b)) * HH + jj];
        float val = (region == 0) ? hy : (region == 1) ? pr
                  : (region == 2) ? (pr - hy) : (hy * pr);
        v[i] = val;
        s += val;
        sq += val * val;
    }
    __shared__ float shs[4], shq[4];
    for (int o = 32; o; o >>= 1) { s += __shfl_down(s, o); sq += __shfl_down(sq, o); }
    int w = tid >> 6, lane = tid & 63;
    if (!lane) { shs[w] = s; shq[w] = sq; }
    __syncthreads();
    s  = shs[0] + shs[1] + shs[2] + shs[3];
    sq = shq[0] + shq[1] + shq[2] + shq[3];
    float mean = s / (float)F4;
    float var  = sq / (float)F4 - mean * mean;
    float rstd = rsqrtf(var + 1e-6f);
#pragma unroll
    for (int i = 0; i < 16; ++i) {
        int e = i * 256 + tid;
        float nv = (v[i] - mean) * rstd * g[e] + be[e];
        f_out[(size_t)b * F4 + e] = f2bf(nv);
    }
}

// ---------------------------------------------------------------------------
// split-K MLP partial GEMM
// ---------------------------------------------------------------------------
template<int KTOT, int NCH>
__global__ __launch_bounds__(256) void k_mlp_sk(
    const bf16* __restrict__ A, const float* __restrict__ Bw,
    float* __restrict__ part)
{
    const int KC = KTOT / NCH;
    const int nb = blockIdx.x, mb = blockIdx.y, kc = blockIdx.z;
    const int w    = threadIdx.x >> 6;
    const int lane = threadIdx.x & 63;
    const int wr = w >> 1, wc = w & 1;
    const int l16 = lane & 15;
    const int kq  = lane >> 4;
    const int m0 = mb * 64 + wr * 32;
    const int c0 = nb * 64 + wc * 32;

    f32x4 acc[2][2];
#pragma unroll
    for (int i = 0; i < 2; ++i)
#pragma unroll
        for (int j = 0; j < 2; ++j) acc[i][j] = (f32x4)0.f;

    for (int kk = kc * (KC / 32); kk < (kc + 1) * (KC / 32); ++kk) {
        const int k0 = kk * 32 + kq * 8;
        short8 a[2], bb[2];
#pragma unroll
        for (int i = 0; i < 2; ++i)
            a[i] = *reinterpret_cast<const short8*>(A + (size_t)(m0 + i * 16 + l16) * KTOT + k0);
#pragma unroll
        for (int j = 0; j < 2; ++j) {
            const float* bp = Bw + (size_t)(c0 + j * 16 + l16) * KTOT + k0;
            float4 v0 = *reinterpret_cast<const float4*>(bp);
            float4 v1 = *reinterpret_cast<const float4*>(bp + 4);
            bb[j] = pack8(v0, v1);
        }
#pragma unroll
        for (int i = 0; i < 2; ++i)
#pragma unroll
            for (int j = 0; j < 2; ++j)
                acc[i][j] = __builtin_amdgcn_mfma_f32_16x16x32_bf16(a[i], bb[j], acc[i][j], 0, 0, 0);
    }
#pragma unroll
    for (int i = 0; i < 2; ++i)
#pragma unroll
        for (int j = 0; j < 2; ++j) {
            int gg = c0 + j * 16 + l16;
#pragma unroll
            for (int q = 0; q < 4; ++q) {
                int m = m0 + i * 16 + kq * 4 + q;
                part[((size_t)kc * TB + m) * HD + gg] = acc[i][j][q];
            }
        }
}

// ---------------------------------------------------------------------------
// fused: reduce partials + bias + relu + LayerNorm(1024) -> bf16
// ---------------------------------------------------------------------------
template<int NCH>
__global__ __launch_bounds__(256) void k_redln(
    const float* __restrict__ part, const float* __restrict__ bias,
    const float* __restrict__ g, const float* __restrict__ be,
    bf16* __restrict__ out)
{
    const int b = blockIdx.x;
    const int tid = threadIdx.x;
    float v[4];
    float s = 0.f, sq = 0.f;
#pragma unroll
    for (int i = 0; i < 4; ++i) {
        int e = i * 256 + tid;
        float val = bias[e];
#pragma unroll
        for (int c = 0; c < NCH; ++c) val += part[((size_t)c * TB + b) * HD + e];
        val = fmaxf(val, 0.f);
        v[i] = val; s += val; sq += val * val;
    }
    __shared__ float shs[4], shq[4];
    for (int o = 32; o; o >>= 1) { s += __shfl_down(s, o); sq += __shfl_down(sq, o); }
    int w = tid >> 6, lane = tid & 63;
    if (!lane) { shs[w] = s; shq[w] = sq; }
    __syncthreads();
    s  = shs[0] + shs[1] + shs[2] + shs[3];
    sq = shq[0] + shq[1] + shq[2] + shq[3];
    float mean = s / (float)HD;
    float var  = sq / (float)HD - mean * mean;
    float rstd = rsqrtf(var + 1e-6f);
#pragma unroll
    for (int i = 0; i < 4; ++i) {
        int e = i * 256 + tid;
        out[(size_t)b * HD + e] = f2bf((v[i] - mean) * rstd * g[e] + be[e]);
    }
}

// ---------------------------------------------------------------------------
// fused: reduce + bias + relu + LayerNorm(1024) + out-proj [128,3] (f32 out)
// ---------------------------------------------------------------------------
template<int NCH>
__global__ __launch_bounds__(256) void k_redln_out(
    const float* __restrict__ part, const float* __restrict__ bias,
    const float* __restrict__ g, const float* __restrict__ be,
    const float* __restrict__ Wt, const float* __restrict__ ob,
    float* __restrict__ out)
{
    const int b = blockIdx.x;
    const int tid = threadIdx.x;
    float v[4];
    float s = 0.f, sq = 0.f;
#pragma unroll
    for (int i = 0; i < 4; ++i) {
        int e = i * 256 + tid;
        float val = bias[e];
#pragma unroll
        for (int c = 0; c < NCH; ++c) val += part[((size_t)c * TB + b) * HD + e];
        val = fmaxf(val, 0.f);
        v[i] = val; s += val; sq += val * val;
    }
    __shared__ float shs[4], shq[4];
    for (int o = 32; o; o >>= 1) { s += __shfl_down(s, o); sq += __shfl_down(sq, o); }
    int w = tid >> 6, lane = tid & 63;
    if (!lane) { shs[w] = s; shq[w] = sq; }
    __syncthreads();
    s  = shs[0] + shs[1] + shs[2] + shs[3];
    sq = shq[0] + shq[1] + shq[2] + shq[3];
    float mean = s / (float)HD;
    float var  = sq / (float)HD - mean * mean;
    float rstd = rsqrtf(var + 1e-6f);
    float p0 = 0.f, p1 = 0.f, p2 = 0.f;
#pragma unroll
    for (int i = 0; i < 4; ++i) {
        int e = i * 256 + tid;
        float f = (v[i] - mean) * rstd * g[e] + be[e];
        p0 += f * Wt[e];
        p1 += f * Wt[HD + e];
        p2 += f * Wt[2 * HD + e];
    }
    for (int o = 32; o; o >>= 1) {
        p0 += __shfl_down(p0, o);
        p1 += __shfl_down(p1, o);
        p2 += __shfl_down(p2, o);
    }
    __shared__ float sh[4][3];
    if (!lane) { sh[w][0] = p0; sh[w][1] = p1; sh[w][2] = p2; }
    __syncthreads();
    if (tid < 3)
        out[b * 3 + tid] = sh[0][tid] + sh[1][tid] + sh[2][tid] + sh[3][tid] + ob[tid];
}

// ---------------------------------------------------------------------------
extern "C" void kernel_launch(void* const* d_in, const int* in_sizes, int n_in,
                              void* d_out, int out_size, void* d_ws, size_t ws_size,
                              hipStream_t stream)
{
    const int*   tok_h  = (const int*)  d_in[0];
    const int*   tok_p  = (const int*)  d_in[1];
    const float* embed  = (const float*)d_in[2];
    const float* W_ih   = (const float*)d_in[3];
    const float* W_hh   = (const float*)d_in[4];
    const float* b_ih   = (const float*)d_in[5];
    const float* b_hh   = (const float*)d_in[6];
    const float* mlp1_W = (const float*)d_in[7];
    const float* mlp1_b = (const float*)d_in[8];
    const float* mlp2_W = (const float*)d_in[9];
    const float* mlp2_b = (const float*)d_in[10];
    const float* out_W  = (const float*)d_in[11];
    const float* out_b  = (const float*)d_in[12];
    const float* ln0_g  = (const float*)d_in[13];
    const float* ln0_b  = (const float*)d_in[14];
    const float* ln1_g  = (const float*)d_in[15];
    const float* ln1_b  = (const float*)d_in[16];
    const float* ln2_g  = (const float*)d_in[17];
    const float* ln2_b  = (const float*)d_in[18];

    char* ws = (char*)d_ws;
    size_t off = 0;
    bf16*  f_ln0 = (bf16*)(ws + off);  off += (size_t)TB * F4 * 2;            // 1 MB
    float* part  = (float*)(ws + off); off += (size_t)8 * TB * HD * 4;        // 4 MB
    bf16*  f_ln1 = (bf16*)(ws + off);  off += (size_t)TB * HD * 2;
    float* h_fin = (float*)(ws + off); off += (size_t)NROWS * HH * 4;         // 1 MB
    bf16*  h_hi  = (bf16*)(ws + off);  off += (size_t)2 * NROWS * HH * 2;     // 1 MB
    bf16*  h_lo  = (bf16*)(ws + off);  off += (size_t)2 * NROWS * HH * 2;     // 1 MB
    int*   slots = (int*)(ws + off);   off += 4096;   // 32 rg x 128B padded
    int*   xinfo = (int*)(ws + off);   off += 4096;
    float* c_buf = (float*)(ws + off); off += (size_t)NROWS * HH * 4;         // 1 MB
    bf16*  W_ihb = (bf16*)(ws + off);  off += (size_t)G4 * EMB * 2;           // 2 MB
    bf16*  W_hhb = (bf16*)(ws + off);  off += (size_t)G4 * HH * 2;            // 2 MB
    // h_f32 (primary): 2 parities x 512 x 512 f32 = 2 MB, aliases h_hi+h_lo
    float* h_f32 = (float*)h_hi;
    // big region: UNION of xg (primary, 128 MB) and x_bf (fallback-1, 32 MB)
    bf16*  xg   = (bf16*)(ws + off);
    bf16*  x_bf = (bf16*)(ws + off);
    const size_t need_primary = off + (size_t)2 * TT * TB * G4 * 2;   // +128 MB
    const size_t need_f1      = off + (size_t)2 * TT * TB * EMB * 2;  // +32 MB

    // zero h region + slots + xinfo (contiguous)
    (void)hipMemsetAsync(h_hi, 0, (size_t)4 * NROWS * HH * 2 + 8192, stream);

    const size_t HS = (size_t)NROWS * HH;
    if (ws_size >= need_primary) {
        k_cvt<<<512, 256, 0, stream>>>(W_ih, W_ihb, G4 * EMB / 4);
        k_xproj3<<<dim3(512, 8), 256, 0, stream>>>(tok_h, tok_p, embed, W_ihb,
                                                   b_ih, b_hh, xg);
        void* args[] = {(void*)&xg, (void*)&W_hh, (void*)&b_ih, (void*)&b_hh,
                        (void*)&h_f32, (void*)&h_fin, (void*)&slots, (void*)&xinfo};
        (void)hipLaunchCooperativeKernel((void*)k_persist11, dim3(256), dim3(512),
                                         args, 0, stream);
    } else if (ws_size >= need_f1) {
        k_gather<<<4096, 256, 0, stream>>>(tok_h, tok_p, embed, x_bf);
        void* args[] = {(void*)&x_bf, (void*)&W_ih, (void*)&W_hh,
                        (void*)&b_ih, (void*)&b_hh,
                        (void*)&h_hi, (void*)&h_lo, (void*)&h_fin, (void*)&slots};
        (void)hipLaunchCooperativeKernel((void*)k_persist, dim3(256), dim3(256),
                                         args, 0, stream);
    } else {
        (void)hipMemsetAsync(c_buf, 0, (size_t)NROWS * HH * 4, stream);
        k_cvt<<<512, 256, 0, stream>>>(W_ih, W_ihb, G4 * EMB / 4);
        k_cvt<<<512, 256, 0, stream>>>(W_hh, W_hhb, G4 * HH / 4);
        for (int t = 0; t < TT; ++t) {
            int p = t & 1;
            k_step<0><<<256, 256, 0, stream>>>(x_bf, embed, tok_h, tok_p,
                W_ihb, W_hhb, b_ih, b_hh,
                h_hi + (size_t)p * HS, h_lo + (size_t)p * HS,
                h_hi + (size_t)(p ^ 1) * HS, h_lo + (size_t)(p ^ 1) * HS,
                c_buf, h_fin, t);
        }
    }

    // head (fused)
    k_feat_ln0<<<TB, 256, 0, stream>>>(h_fin, ln0_g, ln0_b, f_ln0);
    k_mlp_sk<F4, 8><<<dim3(16, 2, 8), 256, 0, stream>>>(f_ln0, mlp1_W, part);
    k_redln<8><<<TB, 256, 0, stream>>>(part, mlp1_b, ln1_g, ln1_b, f_ln1);
    k_mlp_sk<HD, 4><<<dim3(16, 2, 4), 256, 0, stream>>>(f_ln1, mlp2_W, part);
    k_redln_out<4><<<TB, 256, 0, stream>>>(part, mlp2_b, ln2_g, ln2_b,
                                           out_W, out_b, (float*)d_out);
}